// Round 8
// baseline (129.424 us; speedup 1.0000x reference)
//
#include <hip/hip_runtime.h>
#include <cstdint>
#include <cstddef>

#define BB 8
#define CIN 256
#define CMID 16
#define HH 128
#define WW 128
#define HW 16384
#define NANG 8
#define NRAD 9

#define CSPL 4          // proj channel split
#define CCH  64         // CIN / CSPL
#define OSPL 8          // out channel split
#define OCH  32         // CIN / OSPL

#define PROJ_BLOCKS 1024
#define GAIN_BLOCKS 256

// LDS row stride (floats) for the FFT tile: 129 = 1 mod 32 banks -> with
// row-fastest lane mapping every pass is <=2-way bank aliased (free).
#define LDSW 129

typedef float f32x2 __attribute__((ext_vector_type(2)));
typedef float f32x4 __attribute__((ext_vector_type(4)));

static __device__ __forceinline__ float bf2f(unsigned short u) {
  union { unsigned int i; float f; } c; c.i = ((unsigned int)u) << 16; return c.f;
}
static __device__ __forceinline__ unsigned short f2bf(float f) {
  union { float f; unsigned int i; } c; c.f = f;
  unsigned int r = c.i + 0x7FFFu + ((c.i >> 16) & 1u);
  return (unsigned short)(r >> 16);
}

// 2-element load: ISF=fp32 (8B) else bf16 pair (4B). NT = nontemporal hint.
template<bool ISF, bool NT>
static __device__ __forceinline__ float2 load2g(const void* p, size_t i) {
  float2 r;
  if (ISF) {
    if (NT) {
      f32x2 v = __builtin_nontemporal_load(
          reinterpret_cast<const f32x2*>((const float*)p + i));
      r.x = v.x; r.y = v.y;
    } else {
      r = *reinterpret_cast<const float2*>((const float*)p + i);
    }
  } else {
    unsigned int v;
    if (NT) v = __builtin_nontemporal_load(
        reinterpret_cast<const unsigned int*>((const unsigned short*)p + i));
    else    v = *reinterpret_cast<const unsigned int*>((const unsigned short*)p + i);
    r.x = bf2f((unsigned short)(v & 0xffffu));
    r.y = bf2f((unsigned short)(v >> 16));
  }
  return r;
}

// 4-element load: ISF=fp32 (16B) else bf16 quad (8B). NT = nontemporal hint.
template<bool ISF, bool NT>
static __device__ __forceinline__ float4 load4g(const void* p, size_t i) {
  float4 r;
  if (ISF) {
    if (NT) {
      f32x4 v = __builtin_nontemporal_load(
          reinterpret_cast<const f32x4*>((const float*)p + i));
      r.x = v.x; r.y = v.y; r.z = v.z; r.w = v.w;
    } else {
      r = *reinterpret_cast<const float4*>((const float*)p + i);
    }
  } else {
    unsigned long long q;
    if (NT) q = __builtin_nontemporal_load(
        reinterpret_cast<const unsigned long long*>((const unsigned short*)p + i));
    else    q = *reinterpret_cast<const unsigned long long*>((const unsigned short*)p + i);
    r.x = bf2f((unsigned short)(q & 0xffffu));
    r.y = bf2f((unsigned short)((q >> 16) & 0xffffu));
    r.z = bf2f((unsigned short)((q >> 32) & 0xffffu));
    r.w = bf2f((unsigned short)(q >> 48));
  }
  return r;
}

static __device__ __forceinline__ ushort4 f4_to_u4(float4 v) {
  ushort4 o; o.x = f2bf(v.x); o.y = f2bf(v.y); o.z = f2bf(v.z); o.w = f2bf(v.w);
  return o;
}
static __device__ __forceinline__ float4 u64_to_f4(unsigned long long q) {
  float4 o;
  o.x = bf2f((unsigned short)(q & 0xffffu));
  o.y = bf2f((unsigned short)((q >> 16) & 0xffffu));
  o.z = bf2f((unsigned short)((q >> 32) & 0xffffu));
  o.w = bf2f((unsigned short)(q >> 48));
  return o;
}

// In-kernel dtype sniff: one wave ballots wild bf16 exponents in x[0..127]'s
// low ushorts (fp32 mantissa halves -> ~84% wild; bf16 N(0,1) -> ~0%).
#define SNIFF_ISF(xptr, t, s_isf, isf)                                   \
  if ((t) < 64) {                                                        \
    const unsigned short* u16_ = (const unsigned short*)(xptr);          \
    unsigned short us_ = u16_[2 * (t)];                                  \
    int e_ = (us_ >> 7) & 0xff;                                          \
    unsigned long long m_ = __ballot(e_ < 107 || e_ > 147);              \
    if ((t) == 0) (s_isf) = (__popcll(m_) > 32) ? 1 : 0;                 \
  }                                                                      \
  __syncthreads();                                                       \
  isf = (s_isf);

// ---------------- gain body (bit-reversed layout, ortho scale folded) ----------------
static __device__ __forceinline__ void gain_body(const void* bw, float* G, int idx, int isf) {
  int m = idx >> 14;
  int p = (idx >> 7) & 127;
  int q = idx & 127;
  int ky = (int)(__brev((unsigned)p) >> 25);
  int kx = (int)(__brev((unsigned)q) >> 25);
  float fy = (float)((ky < 64) ? ky : ky - 128);
  float fx = (float)((kx < 64) ? kx : kx - 128);
  float r = sqrtf(fy * fy + fx * fx);
  int ridx = (int)(r * 0.125f);
  ridx = (ridx > NRAD - 1) ? (NRAD - 1) : ridx;
  const float PI_F = 3.14159265358979323846f;
  float theta = fmodf(atan2f(fy, fx) + PI_F, PI_F);
  const float delta = PI_F / 8.0f;
  const float hwid = 0.75f * delta;
  float wv[NANG]; float s = 0.f;
#pragma unroll
  for (int a = 0; a < NANG; ++a) {
    float center = ((float)a + 0.5f) * delta;
    float dist = fabsf(theta - center);
    float wa = (dist < hwid) ? (1.0f - dist / hwid) : 0.0f;
    wv[a] = wa; s += wa;
  }
  float inv = 1.0f / (s + 1e-8f);
  float g = 0.f;
#pragma unroll
  for (int a = 0; a < NANG; ++a) {
    int o = (m * NANG + a) * NRAD + ridx;
    float bwa = isf ? ((const float*)bw)[o] : bf2f(((const unsigned short*)bw)[o]);
    g += wv[a] * bwa;
  }
  G[idx] = g * inv * (1.0f / 16384.0f);
}

// ---------------- projection (2 px/thread, unroll 16) + gain blocks merged ----------------
// NOTE: no min-waves __launch_bounds__ — forcing 8 waves/EU caps VGPR at 32 and
// spills the accumulator to scratch (measured R4: WRITE_SIZE 17->205 MB).
template<bool ISF>
static __device__ __forceinline__ void proj_body(const void* x, const float* wl,
                                                 unsigned short* part, int b, int s, int pp) {
  float2 acc[CMID];
#pragma unroll
  for (int m = 0; m < CMID; ++m) { acc[m].x = 0.f; acc[m].y = 0.f; }
  const size_t xbase = (size_t)b * CIN * HW + (size_t)(s * CCH) * HW + pp;
#pragma unroll 16
  for (int cc = 0; cc < CCH; ++cc) {
    float2 xv = load2g<ISF, false>(x, xbase + (size_t)cc * HW);
#pragma unroll
    for (int m = 0; m < CMID; ++m) {
      float w = wl[m * CCH + cc];
      acc[m].x = fmaf(xv.x, w, acc[m].x);
      acc[m].y = fmaf(xv.y, w, acc[m].y);
    }
  }
  unsigned short* pb = part + ((size_t)(s * BB + b) * CMID) * HW + pp;
#pragma unroll
  for (int m = 0; m < CMID; ++m) {
    unsigned int o = (unsigned int)f2bf(acc[m].x) | ((unsigned int)f2bf(acc[m].y) << 16);
    *reinterpret_cast<unsigned int*>(pb + (size_t)m * HW) = o;
  }
}

__global__ __launch_bounds__(256)
void afe_projgain_kernel(const void* __restrict__ x, const void* __restrict__ w_in,
                         const void* __restrict__ bw,
                         unsigned short* __restrict__ part, float* __restrict__ G) {
  __shared__ int s_isf;
  __shared__ float wl[CMID * CCH];
  int t = threadIdx.x;
  int isf;
  SNIFF_ISF(x, t, s_isf, isf);
  if (blockIdx.x >= PROJ_BLOCKS) {
    // gain blocks: 256 blocks x 256 threads x 4 px
    int gb = blockIdx.x - PROJ_BLOCKS;
#pragma unroll
    for (int k = 0; k < 4; ++k) {
      int idx = (gb * 4 + k) * 256 + t;
      gain_body(bw, G, idx, isf);
    }
    return;
  }
  int s = blockIdx.x & (CSPL - 1);
  int tile = blockIdx.x >> 2;
  int b = tile >> 5;                               // 32 tiles (512 px) per (b,s)
  int pp = ((tile & 31) << 9) + (t << 1);
  for (int i = t; i < CMID * CCH; i += 256) {
    int m = i >> 6, cc = i & (CCH - 1);
    int src = m * CIN + s * CCH + cc;
    wl[i] = isf ? ((const float*)w_in)[src] : bf2f(((const unsigned short*)w_in)[src]);
  }
  __syncthreads();
  if (isf) proj_body<true>(x, wl, part, b, s, pp);
  else     proj_body<false>(x, wl, part, b, s, pp);
}

// ---------------- per-image FFT2 -> gain -> IFFT2 ----------------
// Fused two-stage (radix-4-equivalent) passes; pure radix-2 bitrev ordering.
// LDS tile stride = LDSW(129) floats; row passes use row-fastest lane mapping
// so ALL passes are conflict-free (<=2-way aliasing).
__global__ __launch_bounds__(512)
void afe_fft_kernel(const unsigned short* __restrict__ part,
                    unsigned short* __restrict__ xenh,
                    const float* __restrict__ G) {
  __shared__ float sRe[LDSW * HH];
  __shared__ float sIm[LDSW * HH];
  __shared__ float twc[64];
  __shared__ float tws[64];
  int t = threadIdx.x;
  int img = blockIdx.x;                            // b*16 + m
  int m = img & 15;
  const size_t S = (size_t)BB * CMID * HW;
  const unsigned long long* q0 = reinterpret_cast<const unsigned long long*>(part + (size_t)img * HW);
  const unsigned long long* q1 = reinterpret_cast<const unsigned long long*>(part + S + (size_t)img * HW);
  const unsigned long long* q2 = reinterpret_cast<const unsigned long long*>(part + 2 * S + (size_t)img * HW);
  const unsigned long long* q3 = reinterpret_cast<const unsigned long long*>(part + 3 * S + (size_t)img * HW);

#pragma unroll
  for (int i = 0; i < 8; ++i) {
    int i4 = t + 512 * i;                          // float4 index in [0,4096)
    float4 a  = u64_to_f4(__builtin_nontemporal_load(q0 + i4));
    float4 b4 = u64_to_f4(__builtin_nontemporal_load(q1 + i4));
    float4 c4 = u64_to_f4(__builtin_nontemporal_load(q2 + i4));
    float4 d4 = u64_to_f4(__builtin_nontemporal_load(q3 + i4));
    int row = i4 >> 5, colb = (i4 * 4) & 127;
    int p = row * LDSW + colb;
    sRe[p]     = a.x + b4.x + c4.x + d4.x;
    sRe[p + 1] = a.y + b4.y + c4.y + d4.y;
    sRe[p + 2] = a.z + b4.z + c4.z + d4.z;
    sRe[p + 3] = a.w + b4.w + c4.w + d4.w;
    sIm[p] = 0.f; sIm[p + 1] = 0.f; sIm[p + 2] = 0.f; sIm[p + 3] = 0.f;
  }
  if (t < 64) {
    const float PI_F = 3.14159265358979323846f;
    float ang = -(2.0f * PI_F / 128.0f) * (float)t;  // W^t = e^{-i 2 pi t/128}
    float sv, cv;
    sincosf(ang, &sv, &cv);
    twc[t] = cv; tws[t] = sv;
  }

  // ---- forward fused passes (stages s, s-1), s = 7,5,3 ----
#pragma unroll
  for (int si = 0; si < 3; ++si) {
    const int s = 7 - 2 * si;
    const int quarter = 1 << (s - 2);
    const int tstr = 1 << (7 - s);
    // rows (row-fastest lanes: conflict-free)
    __syncthreads();
#pragma unroll
    for (int it = 0; it < 8; ++it) {
      int idx = t + 512 * it;                      // 4096 groups
      int row = idx & 127, gg = idx >> 7;
      int j = gg & (quarter - 1), g = gg >> (s - 2);
      int p1 = row * LDSW + (g << s) + j;
      int p2 = p1 + quarter, p3 = p1 + 2 * quarter, p4 = p3 + quarter;
      int i1 = j * tstr, i3 = 2 * j * tstr;
      float c1 = twc[i1], s1 = tws[i1], c3 = twc[i3], s3 = tws[i3];
      float ar = sRe[p1], ai = sIm[p1], br = sRe[p2], bi = sIm[p2];
      float cr = sRe[p3], ci = sIm[p3], dr = sRe[p4], di = sIm[p4];
      float u1r = ar + cr, u1i = ai + ci, t1r = ar - cr, t1i = ai - ci;
      float u2r = br + dr, u2i = bi + di, t2r = br - dr, t2i = bi - di;
      float w1r = t1r * c1 - t1i * s1, w1i = t1r * s1 + t1i * c1;
      float zr = t2r * c1 - t2i * s1, zi = t2r * s1 + t2i * c1;
      float w2r = zi, w2i = -zr;                   // * (-i)
      float e1r = u1r - u2r, e1i = u1i - u2i;
      float e2r = w1r - w2r, e2i = w1i - w2i;
      sRe[p1] = u1r + u2r; sIm[p1] = u1i + u2i;
      sRe[p2] = e1r * c3 - e1i * s3; sIm[p2] = e1r * s3 + e1i * c3;
      sRe[p3] = w1r + w2r; sIm[p3] = w1i + w2i;
      sRe[p4] = e2r * c3 - e2i * s3; sIm[p4] = e2r * s3 + e2i * c3;
    }
    // cols (col-fastest lanes: conflict-free)
    __syncthreads();
#pragma unroll
    for (int it = 0; it < 8; ++it) {
      int idx = t + 512 * it;
      int col = idx & 127, gg = idx >> 7;
      int j = gg & (quarter - 1), g = gg >> (s - 2);
      int p1 = ((g << s) + j) * LDSW + col;
      int p2 = p1 + quarter * LDSW, p3 = p1 + 2 * quarter * LDSW, p4 = p1 + 3 * quarter * LDSW;
      int i1 = j * tstr, i3 = 2 * j * tstr;
      float c1 = twc[i1], s1 = tws[i1], c3 = twc[i3], s3 = tws[i3];
      float ar = sRe[p1], ai = sIm[p1], br = sRe[p2], bi = sIm[p2];
      float cr = sRe[p3], ci = sIm[p3], dr = sRe[p4], di = sIm[p4];
      float u1r = ar + cr, u1i = ai + ci, t1r = ar - cr, t1i = ai - ci;
      float u2r = br + dr, u2i = bi + di, t2r = br - dr, t2i = bi - di;
      float w1r = t1r * c1 - t1i * s1, w1i = t1r * s1 + t1i * c1;
      float zr = t2r * c1 - t2i * s1, zi = t2r * s1 + t2i * c1;
      float w2r = zi, w2i = -zr;
      float e1r = u1r - u2r, e1i = u1i - u2i;
      float e2r = w1r - w2r, e2i = w1i - w2i;
      sRe[p1] = u1r + u2r; sIm[p1] = u1i + u2i;
      sRe[p2] = e1r * c3 - e1i * s3; sIm[p2] = e1r * s3 + e1i * c3;
      sRe[p3] = w1r + w2r; sIm[p3] = w1i + w2i;
      sRe[p4] = e2r * c3 - e2i * s3; sIm[p4] = e2r * s3 + e2i * c3;
    }
  }
  // ---- forward stage 1 (no twiddle), rows then cols, then gain ----
  __syncthreads();
#pragma unroll
  for (int it = 0; it < 16; ++it) {
    int idx = t + 512 * it;                        // 8192 pairs
    int row = idx & 127, k = idx >> 7;             // k in [0,64)
    int p1 = row * LDSW + (k << 1), p2 = p1 + 1;
    float ur = sRe[p1], ui = sIm[p1], vr = sRe[p2], vi = sIm[p2];
    sRe[p1] = ur + vr; sIm[p1] = ui + vi;
    sRe[p2] = ur - vr; sIm[p2] = ui - vi;
  }
  __syncthreads();
#pragma unroll
  for (int it = 0; it < 16; ++it) {
    int idx = t + 512 * it;
    int col = idx & 127, k = idx >> 7;             // k in [0,64)
    int p1 = (k << 1) * LDSW + col, p2 = p1 + LDSW;
    float ur = sRe[p1], ui = sIm[p1], vr = sRe[p2], vi = sIm[p2];
    sRe[p1] = ur + vr; sIm[p1] = ui + vi;
    sRe[p2] = ur - vr; sIm[p2] = ui - vi;
  }
  __syncthreads();
  {
    const float4* Gm = reinterpret_cast<const float4*>(G + m * HW);
#pragma unroll
    for (int it = 0; it < 8; ++it) {
      int i4 = t + 512 * it;
      float4 g = Gm[i4];
      int row = i4 >> 5, colb = (i4 * 4) & 127;
      int p = row * LDSW + colb;
      sRe[p] *= g.x; sIm[p] *= g.x;
      sRe[p + 1] *= g.y; sIm[p + 1] *= g.y;
      sRe[p + 2] *= g.z; sIm[p + 2] *= g.z;
      sRe[p + 3] *= g.w; sIm[p + 3] *= g.w;
    }
  }
  // ---- inverse stage 1 cols ----
  __syncthreads();
#pragma unroll
  for (int it = 0; it < 16; ++it) {
    int idx = t + 512 * it;
    int col = idx & 127, k = idx >> 7;
    int p1 = (k << 1) * LDSW + col, p2 = p1 + LDSW;
    float ur = sRe[p1], ui = sIm[p1], vr = sRe[p2], vi = sIm[p2];
    sRe[p1] = ur + vr; sIm[p1] = ui + vi;
    sRe[p2] = ur - vr; sIm[p2] = ui - vi;
  }
  // inverse fused passes (stages s-1 then s), s = 3,5,7 — cols
#pragma unroll
  for (int si = 0; si < 3; ++si) {
    const int s = 3 + 2 * si;
    const int quarter = 1 << (s - 2);
    const int tstr = 1 << (7 - s);
    __syncthreads();
#pragma unroll
    for (int it = 0; it < 8; ++it) {
      int idx = t + 512 * it;
      int col = idx & 127, gg = idx >> 7;
      int j = gg & (quarter - 1), g = gg >> (s - 2);
      int p1 = ((g << s) + j) * LDSW + col;
      int p2 = p1 + quarter * LDSW, p3 = p1 + 2 * quarter * LDSW, p4 = p1 + 3 * quarter * LDSW;
      int i1 = j * tstr, i3 = 2 * j * tstr;
      float c1 = twc[i1], s1 = -tws[i1], c3 = twc[i3], s3 = -tws[i3];  // conj
      float ar = sRe[p1], ai = sIm[p1], br = sRe[p2], bi = sIm[p2];
      float cr = sRe[p3], ci = sIm[p3], dr = sRe[p4], di = sIm[p4];
      float btr = br * c3 - bi * s3, bti = br * s3 + bi * c3;
      float dtr = dr * c3 - di * s3, dti = dr * s3 + di * c3;
      float Ar = ar + btr, Ai = ai + bti, Br = ar - btr, Bi = ai - bti;
      float Cr = cr + dtr, Ci = ci + dti, Dr = cr - dtr, Di = ci - dti;
      float Ctr = Cr * c1 - Ci * s1, Cti = Cr * s1 + Ci * c1;
      float z0r = Dr * c1 - Di * s1, z0i = Dr * s1 + Di * c1;
      float Dtr = -z0i, Dti = z0r;                 // * (+i)
      sRe[p1] = Ar + Ctr; sIm[p1] = Ai + Cti;
      sRe[p3] = Ar - Ctr; sIm[p3] = Ai - Cti;
      sRe[p2] = Br + Dtr; sIm[p2] = Bi + Dti;
      sRe[p4] = Br - Dtr; sIm[p4] = Bi - Dti;
    }
  }
  // inverse stage 1 rows
  __syncthreads();
#pragma unroll
  for (int it = 0; it < 16; ++it) {
    int idx = t + 512 * it;
    int row = idx & 127, k = idx >> 7;
    int p1 = row * LDSW + (k << 1), p2 = p1 + 1;
    float ur = sRe[p1], ui = sIm[p1], vr = sRe[p2], vi = sIm[p2];
    sRe[p1] = ur + vr; sIm[p1] = ui + vi;
    sRe[p2] = ur - vr; sIm[p2] = ui - vi;
  }
  // inverse fused passes — rows
#pragma unroll
  for (int si = 0; si < 3; ++si) {
    const int s = 3 + 2 * si;
    const int quarter = 1 << (s - 2);
    const int tstr = 1 << (7 - s);
    __syncthreads();
#pragma unroll
    for (int it = 0; it < 8; ++it) {
      int idx = t + 512 * it;
      int row = idx & 127, gg = idx >> 7;
      int j = gg & (quarter - 1), g = gg >> (s - 2);
      int p1 = row * LDSW + (g << s) + j;
      int p2 = p1 + quarter, p3 = p1 + 2 * quarter, p4 = p3 + quarter;
      int i1 = j * tstr, i3 = 2 * j * tstr;
      float c1 = twc[i1], s1 = -tws[i1], c3 = twc[i3], s3 = -tws[i3];
      float ar = sRe[p1], ai = sIm[p1], br = sRe[p2], bi = sIm[p2];
      float cr = sRe[p3], ci = sIm[p3], dr = sRe[p4], di = sIm[p4];
      float btr = br * c3 - bi * s3, bti = br * s3 + bi * c3;
      float dtr = dr * c3 - di * s3, dti = dr * s3 + di * c3;
      float Ar = ar + btr, Ai = ai + bti, Br = ar - btr, Bi = ai - bti;
      float Cr = cr + dtr, Ci = ci + dti, Dr = cr - dtr, Di = ci - dti;
      float Ctr = Cr * c1 - Ci * s1, Cti = Cr * s1 + Ci * c1;
      float z0r = Dr * c1 - Di * s1, z0i = Dr * s1 + Di * c1;
      float Dtr = -z0i, Dti = z0r;
      sRe[p1] = Ar + Ctr; sIm[p1] = Ai + Cti;
      sRe[p3] = Ar - Ctr; sIm[p3] = Ai - Cti;
      sRe[p2] = Br + Dtr; sIm[p2] = Bi + Dti;
      sRe[p4] = Br - Dtr; sIm[p4] = Bi - Dti;
    }
  }
  __syncthreads();
  // store real part as bf16
  {
    ushort4* xe = reinterpret_cast<ushort4*>(xenh + (size_t)img * HW);
#pragma unroll
    for (int i = 0; i < 8; ++i) {
      int i4 = t + 512 * i;
      int row = i4 >> 5, colb = (i4 * 4) & 127;
      int p = row * LDSW + colb;
      float4 v; v.x = sRe[p]; v.y = sRe[p + 1]; v.z = sRe[p + 2]; v.w = sRe[p + 3];
      xe[i4] = f4_to_u4(v);
    }
  }
}

// ---------------- output: out = x + sum_m xenh[b,m] * w_out[c,m] (4 px/thread, NT) ----------------
template<bool ISF>
static __device__ __forceinline__ void out_body(const void* x, const float* wl,
                                                const unsigned short* xenh, void* out,
                                                int b, int cs, int pp) {
  float4 e[CMID];
  const unsigned short* xe = xenh + (size_t)(b * CMID) * HW + pp;
#pragma unroll
  for (int m = 0; m < CMID; ++m) {
    unsigned long long q = *reinterpret_cast<const unsigned long long*>(xe + (size_t)m * HW);
    e[m] = u64_to_f4(q);
  }
  const size_t off = (size_t)b * CIN * HW + (size_t)(cs * OCH) * HW + pp;
#pragma unroll 4
  for (int r = 0; r < OCH; ++r) {
    float4 xv = load4g<ISF, true>(x, off + (size_t)r * HW);
#pragma unroll
    for (int m = 0; m < CMID; ++m) {
      float w = wl[r * CMID + m];
      xv.x = fmaf(e[m].x, w, xv.x);
      xv.y = fmaf(e[m].y, w, xv.y);
      xv.z = fmaf(e[m].z, w, xv.z);
      xv.w = fmaf(e[m].w, w, xv.w);
    }
    if (ISF) {
      union { float4 f; f32x4 v; } cv; cv.f = xv;
      __builtin_nontemporal_store(cv.v,
          reinterpret_cast<f32x4*>((float*)out + off + (size_t)r * HW));
    } else {
      union { ushort4 u; unsigned long long q; } cv; cv.u = f4_to_u4(xv);
      __builtin_nontemporal_store(cv.q,
          reinterpret_cast<unsigned long long*>((unsigned short*)out + off + (size_t)r * HW));
    }
  }
}

__global__ __launch_bounds__(256)
void afe_out_kernel(const void* __restrict__ x, const void* __restrict__ w_out,
                    const unsigned short* __restrict__ xenh, void* __restrict__ out) {
  __shared__ int s_isf;
  __shared__ float wl[OCH * CMID];
  int t = threadIdx.x;
  int isf;
  SNIFF_ISF(x, t, s_isf, isf);
  int cs = blockIdx.x & (OSPL - 1);
  int tile = blockIdx.x >> 3;
  int b = tile >> 4;                               // 16 tiles (1024 px) per (b,cs)
  int pp = ((tile & 15) << 10) + (t << 2);
  for (int i = t; i < OCH * CMID; i += 256) {
    int r = i >> 4, m = i & 15;
    int src = (cs * OCH + r) * CMID + m;
    wl[i] = isf ? ((const float*)w_out)[src] : bf2f(((const unsigned short*)w_out)[src]);
  }
  __syncthreads();
  if (isf) out_body<true>(x, wl, xenh, out, b, cs, pp);
  else     out_body<false>(x, wl, xenh, out, b, cs, pp);
}

extern "C" void kernel_launch(void* const* d_in, const int* in_sizes, int n_in,
                              void* d_out, int out_size, void* d_ws, size_t ws_size,
                              hipStream_t stream) {
  const void* x      = d_in[0];   // (8,256,128,128)
  const void* w_in   = d_in[1];   // (16,256)
  const void* w_out  = d_in[2];   // (256,16)
  const void* bw     = d_in[3];   // (16,8,9)

  float* G = (float*)d_ws;                                         // 1 MiB fp32
  unsigned short* part = (unsigned short*)(G + CMID * HW);         // 16.8 MiB bf16
  unsigned short* xenh = part + (size_t)CSPL * BB * CMID * HW;     // 4.2 MiB bf16

  hipLaunchKernelGGL(afe_projgain_kernel, dim3(PROJ_BLOCKS + GAIN_BLOCKS), dim3(256), 0, stream,
                     x, w_in, bw, part, G);
  hipLaunchKernelGGL(afe_fft_kernel, dim3(BB * CMID), dim3(512), 0, stream, part, xenh, G);
  hipLaunchKernelGGL(afe_out_kernel, dim3(16 * BB * OSPL), dim3(256), 0, stream, x, w_out, xenh, d_out);
}

// Round 9
// 124.805 us; speedup vs baseline: 1.0370x; 1.0370x over previous
//
#include <hip/hip_runtime.h>
#include <cstdint>
#include <cstddef>

#define BB 8
#define CIN 256
#define CMID 16
#define HH 128
#define WW 128
#define HW 16384
#define NANG 8
#define NRAD 9

#define OSPL 4          // out channel split
#define OCH  64         // CIN / OSPL

#define GAIN_BLOCKS 256

// LDS row stride (floats) for the FFT tile: 129 = 1 mod 32 banks -> with
// row-fastest lane mapping every pass is <=2-way bank aliased (free).
#define LDSW 129

typedef float f32x2 __attribute__((ext_vector_type(2)));

static __device__ __forceinline__ float bf2f(unsigned short u) {
  union { unsigned int i; float f; } c; c.i = ((unsigned int)u) << 16; return c.f;
}
static __device__ __forceinline__ unsigned short f2bf(float f) {
  union { float f; unsigned int i; } c; c.f = f;
  unsigned int r = c.i + 0x7FFFu + ((c.i >> 16) & 1u);
  return (unsigned short)(r >> 16);
}

// 2-element load: ISF=fp32 (8B) else bf16 pair (4B). NT = nontemporal hint.
template<bool ISF, bool NT>
static __device__ __forceinline__ float2 load2g(const void* p, size_t i) {
  float2 r;
  if (ISF) {
    if (NT) {
      f32x2 v = __builtin_nontemporal_load(
          reinterpret_cast<const f32x2*>((const float*)p + i));
      r.x = v.x; r.y = v.y;
    } else {
      r = *reinterpret_cast<const float2*>((const float*)p + i);
    }
  } else {
    unsigned int v;
    if (NT) v = __builtin_nontemporal_load(
        reinterpret_cast<const unsigned int*>((const unsigned short*)p + i));
    else    v = *reinterpret_cast<const unsigned int*>((const unsigned short*)p + i);
    r.x = bf2f((unsigned short)(v & 0xffffu));
    r.y = bf2f((unsigned short)(v >> 16));
  }
  return r;
}

static __device__ __forceinline__ ushort4 f4_to_u4(float4 v) {
  ushort4 o; o.x = f2bf(v.x); o.y = f2bf(v.y); o.z = f2bf(v.z); o.w = f2bf(v.w);
  return o;
}
static __device__ __forceinline__ float4 u64_to_f4(unsigned long long q) {
  float4 o;
  o.x = bf2f((unsigned short)(q & 0xffffu));
  o.y = bf2f((unsigned short)((q >> 16) & 0xffffu));
  o.z = bf2f((unsigned short)((q >> 32) & 0xffffu));
  o.w = bf2f((unsigned short)(q >> 48));
  return o;
}

// In-kernel dtype sniff: one wave ballots wild bf16 exponents in x[0..127]'s
// low ushorts (fp32 mantissa halves -> ~84% wild; bf16 N(0,1) -> ~0%).
#define SNIFF_ISF(xptr, t, s_isf, isf)                                   \
  if ((t) < 64) {                                                        \
    const unsigned short* u16_ = (const unsigned short*)(xptr);          \
    unsigned short us_ = u16_[2 * (t)];                                  \
    int e_ = (us_ >> 7) & 0xff;                                          \
    unsigned long long m_ = __ballot(e_ < 107 || e_ > 147);              \
    if ((t) == 0) (s_isf) = (__popcll(m_) > 32) ? 1 : 0;                 \
  }                                                                      \
  __syncthreads();                                                       \
  isf = (s_isf);

// ---------------- gain body (bit-reversed layout, ortho scale folded) ----------------
static __device__ __forceinline__ void gain_body(const void* bw, float* G, int idx, int isf) {
  int m = idx >> 14;
  int p = (idx >> 7) & 127;
  int q = idx & 127;
  int ky = (int)(__brev((unsigned)p) >> 25);
  int kx = (int)(__brev((unsigned)q) >> 25);
  float fy = (float)((ky < 64) ? ky : ky - 128);
  float fx = (float)((kx < 64) ? kx : kx - 128);
  float r = sqrtf(fy * fy + fx * fx);
  int ridx = (int)(r * 0.125f);
  ridx = (ridx > NRAD - 1) ? (NRAD - 1) : ridx;
  const float PI_F = 3.14159265358979323846f;
  float theta = fmodf(atan2f(fy, fx) + PI_F, PI_F);
  const float delta = PI_F / 8.0f;
  const float hwid = 0.75f * delta;
  float wv[NANG]; float s = 0.f;
#pragma unroll
  for (int a = 0; a < NANG; ++a) {
    float center = ((float)a + 0.5f) * delta;
    float dist = fabsf(theta - center);
    float wa = (dist < hwid) ? (1.0f - dist / hwid) : 0.0f;
    wv[a] = wa; s += wa;
  }
  float inv = 1.0f / (s + 1e-8f);
  float g = 0.f;
#pragma unroll
  for (int a = 0; a < NANG; ++a) {
    int o = (m * NANG + a) * NRAD + ridx;
    float bwa = isf ? ((const float*)bw)[o] : bf2f(((const unsigned short*)bw)[o]);
    g += wv[a] * bwa;
  }
  G[idx] = g * inv * (1.0f / 16384.0f);
}

// ---------------- projection (2 px/thread, unroll 8, NSP-way c-split) ----------------
// NOTE: no min-waves __launch_bounds__ (R4: VGPR cap 32 -> spills) and keep
// body <=64 VGPR for 8 waves/SIMD (R8: unroll16/4px -> >64 VGPR -> 4 waves, -8us).
template<int NSP, bool ISF>
static __device__ __forceinline__ void proj_body(const void* x, const float* wl,
                                                 unsigned short* part, int b, int s, int pp) {
  constexpr int CCHN = CIN / NSP;
  float2 acc[CMID];
#pragma unroll
  for (int m = 0; m < CMID; ++m) { acc[m].x = 0.f; acc[m].y = 0.f; }
  const size_t xbase = (size_t)b * CIN * HW + (size_t)(s * CCHN) * HW + pp;
#pragma unroll 8
  for (int cc = 0; cc < CCHN; ++cc) {
    float2 xv = load2g<ISF, false>(x, xbase + (size_t)cc * HW);
#pragma unroll
    for (int m = 0; m < CMID; ++m) {
      float w = wl[m * CCHN + cc];
      acc[m].x = fmaf(xv.x, w, acc[m].x);
      acc[m].y = fmaf(xv.y, w, acc[m].y);
    }
  }
  unsigned short* pb = part + ((size_t)(s * BB + b) * CMID) * HW + pp;
#pragma unroll
  for (int m = 0; m < CMID; ++m) {
    unsigned int o = (unsigned int)f2bf(acc[m].x) | ((unsigned int)f2bf(acc[m].y) << 16);
    *reinterpret_cast<unsigned int*>(pb + (size_t)m * HW) = o;
  }
}

template<int NSP>
__global__ __launch_bounds__(256)
void afe_projgain_kernel(const void* __restrict__ x, const void* __restrict__ w_in,
                         const void* __restrict__ bw,
                         unsigned short* __restrict__ part, float* __restrict__ G) {
  constexpr int CCHN = CIN / NSP;
  constexpr int LOGN = (NSP == 8) ? 3 : 2;
  constexpr int PROJ_BLOCKS = 32 * BB * NSP;       // 512-px tiles
  __shared__ int s_isf;
  __shared__ float wl[CMID * CCHN];
  int t = threadIdx.x;
  int isf;
  SNIFF_ISF(x, t, s_isf, isf);
  if (blockIdx.x >= PROJ_BLOCKS) {
    // gain blocks: 256 blocks x 256 threads x 4 px
    int gb = blockIdx.x - PROJ_BLOCKS;
#pragma unroll
    for (int k = 0; k < 4; ++k) {
      int idx = (gb * 4 + k) * 256 + t;
      gain_body(bw, G, idx, isf);
    }
    return;
  }
  int s = blockIdx.x & (NSP - 1);
  int tile = blockIdx.x >> LOGN;
  int b = tile >> 5;                               // 32 tiles (512 px) per (b,s)
  int pp = ((tile & 31) << 9) + (t << 1);
  for (int i = t; i < CMID * CCHN; i += 256) {
    int m = i / CCHN, cc = i % CCHN;               // constexpr CCHN -> shifts
    int src = m * CIN + s * CCHN + cc;
    wl[i] = isf ? ((const float*)w_in)[src] : bf2f(((const unsigned short*)w_in)[src]);
  }
  __syncthreads();
  if (isf) proj_body<NSP, true>(x, wl, part, b, s, pp);
  else     proj_body<NSP, false>(x, wl, part, b, s, pp);
}

// ---------------- per-image FFT2 -> gain -> IFFT2 ----------------
// Fused two-stage (radix-4-equivalent) passes; pure radix-2 bitrev ordering.
// LDS tile stride = LDSW(129) floats; row passes use row-fastest lane mapping
// so ALL passes are conflict-free (<=2-way aliasing).
template<int NSP>
__global__ __launch_bounds__(512)
void afe_fft_kernel(const unsigned short* __restrict__ part,
                    unsigned short* __restrict__ xenh,
                    const float* __restrict__ G) {
  __shared__ float sRe[LDSW * HH];
  __shared__ float sIm[LDSW * HH];
  __shared__ float twc[64];
  __shared__ float tws[64];
  int t = threadIdx.x;
  int img = blockIdx.x;                            // b*16 + m
  int m = img & 15;
  const size_t S = (size_t)BB * CMID * HW;
  const unsigned long long* q0 = reinterpret_cast<const unsigned long long*>(part + (size_t)img * HW);

#pragma unroll
  for (int i = 0; i < 8; ++i) {
    int i4 = t + 512 * i;                          // float4 index in [0,4096)
    float4 acc = u64_to_f4(__builtin_nontemporal_load(q0 + i4));
#pragma unroll
    for (int sp = 1; sp < NSP; ++sp) {
      float4 v = u64_to_f4(__builtin_nontemporal_load(
          q0 + (size_t)sp * (S >> 2) + i4));       // S elems = S/4 ull's... (see note)
      acc.x += v.x; acc.y += v.y; acc.z += v.z; acc.w += v.w;
    }
    int row = i4 >> 5, colb = (i4 * 4) & 127;
    int p = row * LDSW + colb;
    sRe[p]     = acc.x;
    sRe[p + 1] = acc.y;
    sRe[p + 2] = acc.z;
    sRe[p + 3] = acc.w;
    sIm[p] = 0.f; sIm[p + 1] = 0.f; sIm[p + 2] = 0.f; sIm[p + 3] = 0.f;
  }
  if (t < 64) {
    const float PI_F = 3.14159265358979323846f;
    float ang = -(2.0f * PI_F / 128.0f) * (float)t;  // W^t = e^{-i 2 pi t/128}
    float sv, cv;
    sincosf(ang, &sv, &cv);
    twc[t] = cv; tws[t] = sv;
  }

  // ---- forward fused passes (stages s, s-1), s = 7,5,3 ----
#pragma unroll
  for (int si = 0; si < 3; ++si) {
    const int s = 7 - 2 * si;
    const int quarter = 1 << (s - 2);
    const int tstr = 1 << (7 - s);
    // rows (row-fastest lanes: conflict-free)
    __syncthreads();
#pragma unroll
    for (int it = 0; it < 8; ++it) {
      int idx = t + 512 * it;                      // 4096 groups
      int row = idx & 127, gg = idx >> 7;
      int j = gg & (quarter - 1), g = gg >> (s - 2);
      int p1 = row * LDSW + (g << s) + j;
      int p2 = p1 + quarter, p3 = p1 + 2 * quarter, p4 = p3 + quarter;
      int i1 = j * tstr, i3 = 2 * j * tstr;
      float c1 = twc[i1], s1 = tws[i1], c3 = twc[i3], s3 = tws[i3];
      float ar = sRe[p1], ai = sIm[p1], br = sRe[p2], bi = sIm[p2];
      float cr = sRe[p3], ci = sIm[p3], dr = sRe[p4], di = sIm[p4];
      float u1r = ar + cr, u1i = ai + ci, t1r = ar - cr, t1i = ai - ci;
      float u2r = br + dr, u2i = bi + di, t2r = br - dr, t2i = bi - di;
      float w1r = t1r * c1 - t1i * s1, w1i = t1r * s1 + t1i * c1;
      float zr = t2r * c1 - t2i * s1, zi = t2r * s1 + t2i * c1;
      float w2r = zi, w2i = -zr;                   // * (-i)
      float e1r = u1r - u2r, e1i = u1i - u2i;
      float e2r = w1r - w2r, e2i = w1i - w2i;
      sRe[p1] = u1r + u2r; sIm[p1] = u1i + u2i;
      sRe[p2] = e1r * c3 - e1i * s3; sIm[p2] = e1r * s3 + e1i * c3;
      sRe[p3] = w1r + w2r; sIm[p3] = w1i + w2i;
      sRe[p4] = e2r * c3 - e2i * s3; sIm[p4] = e2r * s3 + e2i * c3;
    }
    // cols (col-fastest lanes: conflict-free)
    __syncthreads();
#pragma unroll
    for (int it = 0; it < 8; ++it) {
      int idx = t + 512 * it;
      int col = idx & 127, gg = idx >> 7;
      int j = gg & (quarter - 1), g = gg >> (s - 2);
      int p1 = ((g << s) + j) * LDSW + col;
      int p2 = p1 + quarter * LDSW, p3 = p1 + 2 * quarter * LDSW, p4 = p1 + 3 * quarter * LDSW;
      int i1 = j * tstr, i3 = 2 * j * tstr;
      float c1 = twc[i1], s1 = tws[i1], c3 = twc[i3], s3 = tws[i3];
      float ar = sRe[p1], ai = sIm[p1], br = sRe[p2], bi = sIm[p2];
      float cr = sRe[p3], ci = sIm[p3], dr = sRe[p4], di = sIm[p4];
      float u1r = ar + cr, u1i = ai + ci, t1r = ar - cr, t1i = ai - ci;
      float u2r = br + dr, u2i = bi + di, t2r = br - dr, t2i = bi - di;
      float w1r = t1r * c1 - t1i * s1, w1i = t1r * s1 + t1i * c1;
      float zr = t2r * c1 - t2i * s1, zi = t2r * s1 + t2i * c1;
      float w2r = zi, w2i = -zr;
      float e1r = u1r - u2r, e1i = u1i - u2i;
      float e2r = w1r - w2r, e2i = w1i - w2i;
      sRe[p1] = u1r + u2r; sIm[p1] = u1i + u2i;
      sRe[p2] = e1r * c3 - e1i * s3; sIm[p2] = e1r * s3 + e1i * c3;
      sRe[p3] = w1r + w2r; sIm[p3] = w1i + w2i;
      sRe[p4] = e2r * c3 - e2i * s3; sIm[p4] = e2r * s3 + e2i * c3;
    }
  }
  // ---- forward stage 1 (no twiddle), rows then cols, then gain ----
  __syncthreads();
#pragma unroll
  for (int it = 0; it < 16; ++it) {
    int idx = t + 512 * it;                        // 8192 pairs
    int row = idx & 127, k = idx >> 7;             // k in [0,64)
    int p1 = row * LDSW + (k << 1), p2 = p1 + 1;
    float ur = sRe[p1], ui = sIm[p1], vr = sRe[p2], vi = sIm[p2];
    sRe[p1] = ur + vr; sIm[p1] = ui + vi;
    sRe[p2] = ur - vr; sIm[p2] = ui - vi;
  }
  __syncthreads();
#pragma unroll
  for (int it = 0; it < 16; ++it) {
    int idx = t + 512 * it;
    int col = idx & 127, k = idx >> 7;             // k in [0,64)
    int p1 = (k << 1) * LDSW + col, p2 = p1 + LDSW;
    float ur = sRe[p1], ui = sIm[p1], vr = sRe[p2], vi = sIm[p2];
    sRe[p1] = ur + vr; sIm[p1] = ui + vi;
    sRe[p2] = ur - vr; sIm[p2] = ui - vi;
  }
  __syncthreads();
  {
    const float4* Gm = reinterpret_cast<const float4*>(G + m * HW);
#pragma unroll
    for (int it = 0; it < 8; ++it) {
      int i4 = t + 512 * it;
      float4 g = Gm[i4];
      int row = i4 >> 5, colb = (i4 * 4) & 127;
      int p = row * LDSW + colb;
      sRe[p] *= g.x; sIm[p] *= g.x;
      sRe[p + 1] *= g.y; sIm[p + 1] *= g.y;
      sRe[p + 2] *= g.z; sIm[p + 2] *= g.z;
      sRe[p + 3] *= g.w; sIm[p + 3] *= g.w;
    }
  }
  // ---- inverse stage 1 cols ----
  __syncthreads();
#pragma unroll
  for (int it = 0; it < 16; ++it) {
    int idx = t + 512 * it;
    int col = idx & 127, k = idx >> 7;
    int p1 = (k << 1) * LDSW + col, p2 = p1 + LDSW;
    float ur = sRe[p1], ui = sIm[p1], vr = sRe[p2], vi = sIm[p2];
    sRe[p1] = ur + vr; sIm[p1] = ui + vi;
    sRe[p2] = ur - vr; sIm[p2] = ui - vi;
  }
  // inverse fused passes (stages s-1 then s), s = 3,5,7 — cols
#pragma unroll
  for (int si = 0; si < 3; ++si) {
    const int s = 3 + 2 * si;
    const int quarter = 1 << (s - 2);
    const int tstr = 1 << (7 - s);
    __syncthreads();
#pragma unroll
    for (int it = 0; it < 8; ++it) {
      int idx = t + 512 * it;
      int col = idx & 127, gg = idx >> 7;
      int j = gg & (quarter - 1), g = gg >> (s - 2);
      int p1 = ((g << s) + j) * LDSW + col;
      int p2 = p1 + quarter * LDSW, p3 = p1 + 2 * quarter * LDSW, p4 = p1 + 3 * quarter * LDSW;
      int i1 = j * tstr, i3 = 2 * j * tstr;
      float c1 = twc[i1], s1 = -tws[i1], c3 = twc[i3], s3 = -tws[i3];  // conj
      float ar = sRe[p1], ai = sIm[p1], br = sRe[p2], bi = sIm[p2];
      float cr = sRe[p3], ci = sIm[p3], dr = sRe[p4], di = sIm[p4];
      float btr = br * c3 - bi * s3, bti = br * s3 + bi * c3;
      float dtr = dr * c3 - di * s3, dti = dr * s3 + di * c3;
      float Ar = ar + btr, Ai = ai + bti, Br = ar - btr, Bi = ai - bti;
      float Cr = cr + dtr, Ci = ci + dti, Dr = cr - dtr, Di = ci - dti;
      float Ctr = Cr * c1 - Ci * s1, Cti = Cr * s1 + Ci * c1;
      float z0r = Dr * c1 - Di * s1, z0i = Dr * s1 + Di * c1;
      float Dtr = -z0i, Dti = z0r;                 // * (+i)
      sRe[p1] = Ar + Ctr; sIm[p1] = Ai + Cti;
      sRe[p3] = Ar - Ctr; sIm[p3] = Ai - Cti;
      sRe[p2] = Br + Dtr; sIm[p2] = Bi + Dti;
      sRe[p4] = Br - Dtr; sIm[p4] = Bi - Dti;
    }
  }
  // inverse stage 1 rows
  __syncthreads();
#pragma unroll
  for (int it = 0; it < 16; ++it) {
    int idx = t + 512 * it;
    int row = idx & 127, k = idx >> 7;
    int p1 = row * LDSW + (k << 1), p2 = p1 + 1;
    float ur = sRe[p1], ui = sIm[p1], vr = sRe[p2], vi = sIm[p2];
    sRe[p1] = ur + vr; sIm[p1] = ui + vi;
    sRe[p2] = ur - vr; sIm[p2] = ui - vi;
  }
  // inverse fused passes — rows
#pragma unroll
  for (int si = 0; si < 3; ++si) {
    const int s = 3 + 2 * si;
    const int quarter = 1 << (s - 2);
    const int tstr = 1 << (7 - s);
    __syncthreads();
#pragma unroll
    for (int it = 0; it < 8; ++it) {
      int idx = t + 512 * it;
      int row = idx & 127, gg = idx >> 7;
      int j = gg & (quarter - 1), g = gg >> (s - 2);
      int p1 = row * LDSW + (g << s) + j;
      int p2 = p1 + quarter, p3 = p1 + 2 * quarter, p4 = p3 + quarter;
      int i1 = j * tstr, i3 = 2 * j * tstr;
      float c1 = twc[i1], s1 = -tws[i1], c3 = twc[i3], s3 = -tws[i3];
      float ar = sRe[p1], ai = sIm[p1], br = sRe[p2], bi = sIm[p2];
      float cr = sRe[p3], ci = sIm[p3], dr = sRe[p4], di = sIm[p4];
      float btr = br * c3 - bi * s3, bti = br * s3 + bi * c3;
      float dtr = dr * c3 - di * s3, dti = dr * s3 + di * c3;
      float Ar = ar + btr, Ai = ai + bti, Br = ar - btr, Bi = ai - bti;
      float Cr = cr + dtr, Ci = ci + dti, Dr = cr - dtr, Di = ci - dti;
      float Ctr = Cr * c1 - Ci * s1, Cti = Cr * s1 + Ci * c1;
      float z0r = Dr * c1 - Di * s1, z0i = Dr * s1 + Di * c1;
      float Dtr = -z0i, Dti = z0r;
      sRe[p1] = Ar + Ctr; sIm[p1] = Ai + Cti;
      sRe[p3] = Ar - Ctr; sIm[p3] = Ai - Cti;
      sRe[p2] = Br + Dtr; sIm[p2] = Bi + Dti;
      sRe[p4] = Br - Dtr; sIm[p4] = Bi - Dti;
    }
  }
  __syncthreads();
  // store real part as bf16
  {
    ushort4* xe = reinterpret_cast<ushort4*>(xenh + (size_t)img * HW);
#pragma unroll
    for (int i = 0; i < 8; ++i) {
      int i4 = t + 512 * i;
      int row = i4 >> 5, colb = (i4 * 4) & 127;
      int p = row * LDSW + colb;
      float4 v; v.x = sRe[p]; v.y = sRe[p + 1]; v.z = sRe[p + 2]; v.w = sRe[p + 3];
      xe[i4] = f4_to_u4(v);
    }
  }
}

// ---------------- output: out = x + sum_m xenh[b,m] * w_out[c,m] (2 px/thread, NT) ----------------
template<bool ISF>
static __device__ __forceinline__ void out_body(const void* x, const float* wl,
                                                const unsigned short* xenh, void* out,
                                                int b, int cs, int pp) {
  float2 e[CMID];
  const unsigned short* xe = xenh + (size_t)(b * CMID) * HW + pp;
#pragma unroll
  for (int m = 0; m < CMID; ++m) {
    unsigned int v = *reinterpret_cast<const unsigned int*>(xe + (size_t)m * HW);
    e[m].x = bf2f((unsigned short)(v & 0xffffu));
    e[m].y = bf2f((unsigned short)(v >> 16));
  }
  const size_t off = (size_t)b * CIN * HW + (size_t)(cs * OCH) * HW + pp;
#pragma unroll 8
  for (int r = 0; r < OCH; ++r) {
    float2 xv = load2g<ISF, true>(x, off + (size_t)r * HW);
#pragma unroll
    for (int m = 0; m < CMID; ++m) {
      float w = wl[r * CMID + m];
      xv.x = fmaf(e[m].x, w, xv.x);
      xv.y = fmaf(e[m].y, w, xv.y);
    }
    if (ISF) {
      union { float2 f; unsigned long long u; } cv; cv.f = xv;
      __builtin_nontemporal_store(cv.u,
          reinterpret_cast<unsigned long long*>((float*)out + off + (size_t)r * HW));
    } else {
      unsigned int o = (unsigned int)f2bf(xv.x) | ((unsigned int)f2bf(xv.y) << 16);
      __builtin_nontemporal_store(o,
          reinterpret_cast<unsigned int*>((unsigned short*)out + off + (size_t)r * HW));
    }
  }
}

__global__ __launch_bounds__(256)
void afe_out_kernel(const void* __restrict__ x, const void* __restrict__ w_out,
                    const unsigned short* __restrict__ xenh, void* __restrict__ out) {
  __shared__ int s_isf;
  __shared__ float wl[OCH * CMID];
  int t = threadIdx.x;
  int isf;
  SNIFF_ISF(x, t, s_isf, isf);
  int cs = blockIdx.x & (OSPL - 1);
  int tile = blockIdx.x >> 2;
  int b = tile >> 5;                               // 32 tiles (512 px) per (b,cs)
  int pp = ((tile & 31) << 9) + (t << 1);
  for (int i = t; i < OCH * CMID; i += 256) {
    int r = i >> 4, m = i & 15;
    int src = (cs * OCH + r) * CMID + m;
    wl[i] = isf ? ((const float*)w_out)[src] : bf2f(((const unsigned short*)w_out)[src]);
  }
  __syncthreads();
  if (isf) out_body<true>(x, wl, xenh, out, b, cs, pp);
  else     out_body<false>(x, wl, xenh, out, b, cs, pp);
}

extern "C" void kernel_launch(void* const* d_in, const int* in_sizes, int n_in,
                              void* d_out, int out_size, void* d_ws, size_t ws_size,
                              hipStream_t stream) {
  const void* x      = d_in[0];   // (8,256,128,128)
  const void* w_in   = d_in[1];   // (16,256)
  const void* w_out  = d_in[2];   // (256,16)
  const void* bw     = d_in[3];   // (16,8,9)

  float* G = (float*)d_ws;                                         // 1 MiB fp32
  unsigned short* part = (unsigned short*)(G + CMID * HW);
  const size_t S = (size_t)BB * CMID * HW;                         // elems per split

  // NSP=8 needs G(1MB) + part(33.6MB) + xenh(4.2MB); fall back to NSP=4 (R7
  // config) if d_ws is too small. ws_size is fixed per harness -> deterministic.
  size_t need8 = sizeof(float) * CMID * HW + 2 * (8 * S + S) + 256;
  if (ws_size >= need8) {
    unsigned short* xenh = part + 8 * S;
    hipLaunchKernelGGL((afe_projgain_kernel<8>), dim3(32 * BB * 8 + GAIN_BLOCKS), dim3(256),
                       0, stream, x, w_in, bw, part, G);
    hipLaunchKernelGGL((afe_fft_kernel<8>), dim3(BB * CMID), dim3(512), 0, stream,
                       part, xenh, G);
    hipLaunchKernelGGL(afe_out_kernel, dim3(32 * BB * OSPL), dim3(256), 0, stream,
                       x, w_out, xenh, d_out);
  } else {
    unsigned short* xenh = part + 4 * S;
    hipLaunchKernelGGL((afe_projgain_kernel<4>), dim3(32 * BB * 4 + GAIN_BLOCKS), dim3(256),
                       0, stream, x, w_in, bw, part, G);
    hipLaunchKernelGGL((afe_fft_kernel<4>), dim3(BB * CMID), dim3(512), 0, stream,
                       part, xenh, G);
    hipLaunchKernelGGL(afe_out_kernel, dim3(32 * BB * OSPL), dim3(256), 0, stream,
                       x, w_out, xenh, d_out);
  }
}

// Round 10
// 123.640 us; speedup vs baseline: 1.0468x; 1.0094x over previous
//
#include <hip/hip_runtime.h>
#include <cstdint>
#include <cstddef>

#define BB 8
#define CIN 256
#define CMID 16
#define HH 128
#define WW 128
#define HW 16384
#define NANG 8
#define NRAD 9

#define CSPL 4          // proj channel split
#define CCH  64         // CIN / CSPL
#define OSPL 4          // out channel split
#define OCH  64         // CIN / OSPL

#define PROJ_BLOCKS 1024
#define GAIN_BLOCKS 256

// LDS row stride (floats) for the FFT tile: 129 = 1 mod 32 banks -> with
// row-fastest lane mapping every pass is <=2-way bank aliased (free).
#define LDSW 129

typedef float f32x2 __attribute__((ext_vector_type(2)));

static __device__ __forceinline__ float bf2f(unsigned short u) {
  union { unsigned int i; float f; } c; c.i = ((unsigned int)u) << 16; return c.f;
}
static __device__ __forceinline__ unsigned short f2bf(float f) {
  union { float f; unsigned int i; } c; c.f = f;
  unsigned int r = c.i + 0x7FFFu + ((c.i >> 16) & 1u);
  return (unsigned short)(r >> 16);
}

// 2-element load: ISF=fp32 (8B) else bf16 pair (4B). NT = nontemporal hint.
template<bool ISF, bool NT>
static __device__ __forceinline__ float2 load2g(const void* p, size_t i) {
  float2 r;
  if (ISF) {
    if (NT) {
      f32x2 v = __builtin_nontemporal_load(
          reinterpret_cast<const f32x2*>((const float*)p + i));
      r.x = v.x; r.y = v.y;
    } else {
      r = *reinterpret_cast<const float2*>((const float*)p + i);
    }
  } else {
    unsigned int v;
    if (NT) v = __builtin_nontemporal_load(
        reinterpret_cast<const unsigned int*>((const unsigned short*)p + i));
    else    v = *reinterpret_cast<const unsigned int*>((const unsigned short*)p + i);
    r.x = bf2f((unsigned short)(v & 0xffffu));
    r.y = bf2f((unsigned short)(v >> 16));
  }
  return r;
}

static __device__ __forceinline__ ushort4 f4_to_u4(float4 v) {
  ushort4 o; o.x = f2bf(v.x); o.y = f2bf(v.y); o.z = f2bf(v.z); o.w = f2bf(v.w);
  return o;
}
static __device__ __forceinline__ float4 u64_to_f4(unsigned long long q) {
  float4 o;
  o.x = bf2f((unsigned short)(q & 0xffffu));
  o.y = bf2f((unsigned short)((q >> 16) & 0xffffu));
  o.z = bf2f((unsigned short)((q >> 32) & 0xffffu));
  o.w = bf2f((unsigned short)(q >> 48));
  return o;
}

// Per-wave dtype sniff (no barrier, no LDS): every wave ballots wild bf16
// exponents over x[0..127]'s low ushorts (fp32 mantissa halves -> ~84% wild;
// bf16 N(0,1) -> ~0%). All waves reach the same verdict -> uniform branch.
static __device__ __forceinline__ int sniff_isf(const void* x) {
  const unsigned short* u16 = (const unsigned short*)x;
  int lane = threadIdx.x & 63;
  unsigned short us = u16[2 * lane];
  int e = (us >> 7) & 0xff;
  unsigned long long m = __ballot(e < 107 || e > 147);
  return (__popcll(m) > 32) ? 1 : 0;
}

// ---------------- gain body (bit-reversed layout, ortho scale folded) ----------------
static __device__ __forceinline__ void gain_body(const void* bw, float* G, int idx, int isf) {
  int m = idx >> 14;
  int p = (idx >> 7) & 127;
  int q = idx & 127;
  int ky = (int)(__brev((unsigned)p) >> 25);
  int kx = (int)(__brev((unsigned)q) >> 25);
  float fy = (float)((ky < 64) ? ky : ky - 128);
  float fx = (float)((kx < 64) ? kx : kx - 128);
  float r = sqrtf(fy * fy + fx * fx);
  int ridx = (int)(r * 0.125f);
  ridx = (ridx > NRAD - 1) ? (NRAD - 1) : ridx;
  const float PI_F = 3.14159265358979323846f;
  float theta = fmodf(atan2f(fy, fx) + PI_F, PI_F);
  const float delta = PI_F / 8.0f;
  const float hwid = 0.75f * delta;
  float wv[NANG]; float s = 0.f;
#pragma unroll
  for (int a = 0; a < NANG; ++a) {
    float center = ((float)a + 0.5f) * delta;
    float dist = fabsf(theta - center);
    float wa = (dist < hwid) ? (1.0f - dist / hwid) : 0.0f;
    wv[a] = wa; s += wa;
  }
  float inv = 1.0f / (s + 1e-8f);
  float g = 0.f;
#pragma unroll
  for (int a = 0; a < NANG; ++a) {
    int o = (m * NANG + a) * NRAD + ridx;
    float bwa = isf ? ((const float*)bw)[o] : bf2f(((const unsigned short*)bw)[o]);
    g += wv[a] * bwa;
  }
  G[idx] = g * inv * (1.0f / 16384.0f);
}

// ---------------- projection (2 px/thread, SW-pipelined 4-ch windows) ----------------
// NOTE: no min-waves __launch_bounds__ (R4: VGPR cap 32 -> spills). Keep body
// <=64 VGPR for 8 waves/SIMD (R8: bigger bodies -> 4 waves/SIMD, regression).
// Explicit 2-stage pipeline: window w+1's 4 loads issue BEFORE window w's FMA
// burst, so each wave keeps loads in flight through its VALU phase.
template<bool ISF>
static __device__ __forceinline__ void proj_body(const void* x, const float* wl,
                                                 unsigned short* part, int b, int s, int pp) {
  float2 acc[CMID];
#pragma unroll
  for (int m = 0; m < CMID; ++m) { acc[m].x = 0.f; acc[m].y = 0.f; }
  const size_t xbase = (size_t)b * CIN * HW + (size_t)(s * CCH) * HW + pp;

  float2 bufA[4], bufB[4];
#pragma unroll
  for (int k = 0; k < 4; ++k)
    bufA[k] = load2g<ISF, false>(x, xbase + (size_t)k * HW);

#pragma unroll
  for (int w = 0; w < CCH / 4; ++w) {              // 16 windows, fully unrolled
    const bool cura = ((w & 1) == 0);
    if (w < CCH / 4 - 1) {
#pragma unroll
      for (int k = 0; k < 4; ++k) {
        float2 v = load2g<ISF, false>(x, xbase + (size_t)((w + 1) * 4 + k) * HW);
        if (cura) bufB[k] = v; else bufA[k] = v;
      }
    }
#pragma unroll
    for (int k = 0; k < 4; ++k) {
      float2 xv = cura ? bufA[k] : bufB[k];
      const float* wc = wl + (w * 4 + k);
#pragma unroll
      for (int m = 0; m < CMID; ++m) {
        float wgt = wc[m * CCH];
        acc[m].x = fmaf(xv.x, wgt, acc[m].x);
        acc[m].y = fmaf(xv.y, wgt, acc[m].y);
      }
    }
  }
  unsigned short* pb = part + ((size_t)(s * BB + b) * CMID) * HW + pp;
#pragma unroll
  for (int m = 0; m < CMID; ++m) {
    unsigned int o = (unsigned int)f2bf(acc[m].x) | ((unsigned int)f2bf(acc[m].y) << 16);
    *reinterpret_cast<unsigned int*>(pb + (size_t)m * HW) = o;
  }
}

__global__ __launch_bounds__(256)
void afe_projgain_kernel(const void* __restrict__ x, const void* __restrict__ w_in,
                         const void* __restrict__ bw,
                         unsigned short* __restrict__ part, float* __restrict__ G) {
  __shared__ float wl[CMID * CCH];
  int t = threadIdx.x;
  int isf = sniff_isf(x);
  if (blockIdx.x >= PROJ_BLOCKS) {
    // gain blocks: 256 blocks x 256 threads x 4 px
    int gb = blockIdx.x - PROJ_BLOCKS;
#pragma unroll
    for (int k = 0; k < 4; ++k) {
      int idx = (gb * 4 + k) * 256 + t;
      gain_body(bw, G, idx, isf);
    }
    return;
  }
  int s = blockIdx.x & (CSPL - 1);
  int tile = blockIdx.x >> 2;
  int b = tile >> 5;                               // 32 tiles (512 px) per (b,s)
  int pp = ((tile & 31) << 9) + (t << 1);
  for (int i = t; i < CMID * CCH; i += 256) {
    int m = i >> 6, cc = i & (CCH - 1);
    int src = m * CIN + s * CCH + cc;
    wl[i] = isf ? ((const float*)w_in)[src] : bf2f(((const unsigned short*)w_in)[src]);
  }
  __syncthreads();
  if (isf) proj_body<true>(x, wl, part, b, s, pp);
  else     proj_body<false>(x, wl, part, b, s, pp);
}

// ---------------- per-image FFT2 -> gain -> IFFT2 ----------------
// Fused two-stage (radix-4-equivalent) passes; pure radix-2 bitrev ordering.
// LDS tile stride = LDSW(129) floats; row passes use row-fastest lane mapping
// so ALL passes are conflict-free (<=2-way aliasing).
__global__ __launch_bounds__(512)
void afe_fft_kernel(const unsigned short* __restrict__ part,
                    unsigned short* __restrict__ xenh,
                    const float* __restrict__ G) {
  __shared__ float sRe[LDSW * HH];
  __shared__ float sIm[LDSW * HH];
  __shared__ float twc[64];
  __shared__ float tws[64];
  int t = threadIdx.x;
  int img = blockIdx.x;                            // b*16 + m
  int m = img & 15;
  const size_t S = (size_t)BB * CMID * HW;
  const unsigned long long* q0 = reinterpret_cast<const unsigned long long*>(part + (size_t)img * HW);
  const unsigned long long* q1 = reinterpret_cast<const unsigned long long*>(part + S + (size_t)img * HW);
  const unsigned long long* q2 = reinterpret_cast<const unsigned long long*>(part + 2 * S + (size_t)img * HW);
  const unsigned long long* q3 = reinterpret_cast<const unsigned long long*>(part + 3 * S + (size_t)img * HW);

#pragma unroll
  for (int i = 0; i < 8; ++i) {
    int i4 = t + 512 * i;                          // float4 index in [0,4096)
    float4 a  = u64_to_f4(__builtin_nontemporal_load(q0 + i4));
    float4 b4 = u64_to_f4(__builtin_nontemporal_load(q1 + i4));
    float4 c4 = u64_to_f4(__builtin_nontemporal_load(q2 + i4));
    float4 d4 = u64_to_f4(__builtin_nontemporal_load(q3 + i4));
    int row = i4 >> 5, colb = (i4 * 4) & 127;
    int p = row * LDSW + colb;
    sRe[p]     = a.x + b4.x + c4.x + d4.x;
    sRe[p + 1] = a.y + b4.y + c4.y + d4.y;
    sRe[p + 2] = a.z + b4.z + c4.z + d4.z;
    sRe[p + 3] = a.w + b4.w + c4.w + d4.w;
    sIm[p] = 0.f; sIm[p + 1] = 0.f; sIm[p + 2] = 0.f; sIm[p + 3] = 0.f;
  }
  if (t < 64) {
    const float PI_F = 3.14159265358979323846f;
    float ang = -(2.0f * PI_F / 128.0f) * (float)t;  // W^t = e^{-i 2 pi t/128}
    float sv, cv;
    sincosf(ang, &sv, &cv);
    twc[t] = cv; tws[t] = sv;
  }

  // ---- forward fused passes (stages s, s-1), s = 7,5,3 ----
#pragma unroll
  for (int si = 0; si < 3; ++si) {
    const int s = 7 - 2 * si;
    const int quarter = 1 << (s - 2);
    const int tstr = 1 << (7 - s);
    // rows (row-fastest lanes: conflict-free)
    __syncthreads();
#pragma unroll
    for (int it = 0; it < 8; ++it) {
      int idx = t + 512 * it;                      // 4096 groups
      int row = idx & 127, gg = idx >> 7;
      int j = gg & (quarter - 1), g = gg >> (s - 2);
      int p1 = row * LDSW + (g << s) + j;
      int p2 = p1 + quarter, p3 = p1 + 2 * quarter, p4 = p3 + quarter;
      int i1 = j * tstr, i3 = 2 * j * tstr;
      float c1 = twc[i1], s1 = tws[i1], c3 = twc[i3], s3 = tws[i3];
      float ar = sRe[p1], ai = sIm[p1], br = sRe[p2], bi = sIm[p2];
      float cr = sRe[p3], ci = sIm[p3], dr = sRe[p4], di = sIm[p4];
      float u1r = ar + cr, u1i = ai + ci, t1r = ar - cr, t1i = ai - ci;
      float u2r = br + dr, u2i = bi + di, t2r = br - dr, t2i = bi - di;
      float w1r = t1r * c1 - t1i * s1, w1i = t1r * s1 + t1i * c1;
      float zr = t2r * c1 - t2i * s1, zi = t2r * s1 + t2i * c1;
      float w2r = zi, w2i = -zr;                   // * (-i)
      float e1r = u1r - u2r, e1i = u1i - u2i;
      float e2r = w1r - w2r, e2i = w1i - w2i;
      sRe[p1] = u1r + u2r; sIm[p1] = u1i + u2i;
      sRe[p2] = e1r * c3 - e1i * s3; sIm[p2] = e1r * s3 + e1i * c3;
      sRe[p3] = w1r + w2r; sIm[p3] = w1i + w2i;
      sRe[p4] = e2r * c3 - e2i * s3; sIm[p4] = e2r * s3 + e2i * c3;
    }
    // cols (col-fastest lanes: conflict-free)
    __syncthreads();
#pragma unroll
    for (int it = 0; it < 8; ++it) {
      int idx = t + 512 * it;
      int col = idx & 127, gg = idx >> 7;
      int j = gg & (quarter - 1), g = gg >> (s - 2);
      int p1 = ((g << s) + j) * LDSW + col;
      int p2 = p1 + quarter * LDSW, p3 = p1 + 2 * quarter * LDSW, p4 = p1 + 3 * quarter * LDSW;
      int i1 = j * tstr, i3 = 2 * j * tstr;
      float c1 = twc[i1], s1 = tws[i1], c3 = twc[i3], s3 = tws[i3];
      float ar = sRe[p1], ai = sIm[p1], br = sRe[p2], bi = sIm[p2];
      float cr = sRe[p3], ci = sIm[p3], dr = sRe[p4], di = sIm[p4];
      float u1r = ar + cr, u1i = ai + ci, t1r = ar - cr, t1i = ai - ci;
      float u2r = br + dr, u2i = bi + di, t2r = br - dr, t2i = bi - di;
      float w1r = t1r * c1 - t1i * s1, w1i = t1r * s1 + t1i * c1;
      float zr = t2r * c1 - t2i * s1, zi = t2r * s1 + t2i * c1;
      float w2r = zi, w2i = -zr;
      float e1r = u1r - u2r, e1i = u1i - u2i;
      float e2r = w1r - w2r, e2i = w1i - w2i;
      sRe[p1] = u1r + u2r; sIm[p1] = u1i + u2i;
      sRe[p2] = e1r * c3 - e1i * s3; sIm[p2] = e1r * s3 + e1i * c3;
      sRe[p3] = w1r + w2r; sIm[p3] = w1i + w2i;
      sRe[p4] = e2r * c3 - e2i * s3; sIm[p4] = e2r * s3 + e2i * c3;
    }
  }
  // ---- forward stage 1 (no twiddle), rows then cols, then gain ----
  __syncthreads();
#pragma unroll
  for (int it = 0; it < 16; ++it) {
    int idx = t + 512 * it;                        // 8192 pairs
    int row = idx & 127, k = idx >> 7;             // k in [0,64)
    int p1 = row * LDSW + (k << 1), p2 = p1 + 1;
    float ur = sRe[p1], ui = sIm[p1], vr = sRe[p2], vi = sIm[p2];
    sRe[p1] = ur + vr; sIm[p1] = ui + vi;
    sRe[p2] = ur - vr; sIm[p2] = ui - vi;
  }
  __syncthreads();
#pragma unroll
  for (int it = 0; it < 16; ++it) {
    int idx = t + 512 * it;
    int col = idx & 127, k = idx >> 7;             // k in [0,64)
    int p1 = (k << 1) * LDSW + col, p2 = p1 + LDSW;
    float ur = sRe[p1], ui = sIm[p1], vr = sRe[p2], vi = sIm[p2];
    sRe[p1] = ur + vr; sIm[p1] = ui + vi;
    sRe[p2] = ur - vr; sIm[p2] = ui - vi;
  }
  __syncthreads();
  {
    const float4* Gm = reinterpret_cast<const float4*>(G + m * HW);
#pragma unroll
    for (int it = 0; it < 8; ++it) {
      int i4 = t + 512 * it;
      float4 g = Gm[i4];
      int row = i4 >> 5, colb = (i4 * 4) & 127;
      int p = row * LDSW + colb;
      sRe[p] *= g.x; sIm[p] *= g.x;
      sRe[p + 1] *= g.y; sIm[p + 1] *= g.y;
      sRe[p + 2] *= g.z; sIm[p + 2] *= g.z;
      sRe[p + 3] *= g.w; sIm[p + 3] *= g.w;
    }
  }
  // ---- inverse stage 1 cols ----
  __syncthreads();
#pragma unroll
  for (int it = 0; it < 16; ++it) {
    int idx = t + 512 * it;
    int col = idx & 127, k = idx >> 7;
    int p1 = (k << 1) * LDSW + col, p2 = p1 + LDSW;
    float ur = sRe[p1], ui = sIm[p1], vr = sRe[p2], vi = sIm[p2];
    sRe[p1] = ur + vr; sIm[p1] = ui + vi;
    sRe[p2] = ur - vr; sIm[p2] = ui - vi;
  }
  // inverse fused passes (stages s-1 then s), s = 3,5,7 — cols
#pragma unroll
  for (int si = 0; si < 3; ++si) {
    const int s = 3 + 2 * si;
    const int quarter = 1 << (s - 2);
    const int tstr = 1 << (7 - s);
    __syncthreads();
#pragma unroll
    for (int it = 0; it < 8; ++it) {
      int idx = t + 512 * it;
      int col = idx & 127, gg = idx >> 7;
      int j = gg & (quarter - 1), g = gg >> (s - 2);
      int p1 = ((g << s) + j) * LDSW + col;
      int p2 = p1 + quarter * LDSW, p3 = p1 + 2 * quarter * LDSW, p4 = p1 + 3 * quarter * LDSW;
      int i1 = j * tstr, i3 = 2 * j * tstr;
      float c1 = twc[i1], s1 = -tws[i1], c3 = twc[i3], s3 = -tws[i3];  // conj
      float ar = sRe[p1], ai = sIm[p1], br = sRe[p2], bi = sIm[p2];
      float cr = sRe[p3], ci = sIm[p3], dr = sRe[p4], di = sIm[p4];
      float btr = br * c3 - bi * s3, bti = br * s3 + bi * c3;
      float dtr = dr * c3 - di * s3, dti = dr * s3 + di * c3;
      float Ar = ar + btr, Ai = ai + bti, Br = ar - btr, Bi = ai - bti;
      float Cr = cr + dtr, Ci = ci + dti, Dr = cr - dtr, Di = ci - dti;
      float Ctr = Cr * c1 - Ci * s1, Cti = Cr * s1 + Ci * c1;
      float z0r = Dr * c1 - Di * s1, z0i = Dr * s1 + Di * c1;
      float Dtr = -z0i, Dti = z0r;                 // * (+i)
      sRe[p1] = Ar + Ctr; sIm[p1] = Ai + Cti;
      sRe[p3] = Ar - Ctr; sIm[p3] = Ai - Cti;
      sRe[p2] = Br + Dtr; sIm[p2] = Bi + Dti;
      sRe[p4] = Br - Dtr; sIm[p4] = Bi - Dti;
    }
  }
  // inverse stage 1 rows
  __syncthreads();
#pragma unroll
  for (int it = 0; it < 16; ++it) {
    int idx = t + 512 * it;
    int row = idx & 127, k = idx >> 7;
    int p1 = row * LDSW + (k << 1), p2 = p1 + 1;
    float ur = sRe[p1], ui = sIm[p1], vr = sRe[p2], vi = sIm[p2];
    sRe[p1] = ur + vr; sIm[p1] = ui + vi;
    sRe[p2] = ur - vr; sIm[p2] = ui - vi;
  }
  // inverse fused passes — rows
#pragma unroll
  for (int si = 0; si < 3; ++si) {
    const int s = 3 + 2 * si;
    const int quarter = 1 << (s - 2);
    const int tstr = 1 << (7 - s);
    __syncthreads();
#pragma unroll
    for (int it = 0; it < 8; ++it) {
      int idx = t + 512 * it;
      int row = idx & 127, gg = idx >> 7;
      int j = gg & (quarter - 1), g = gg >> (s - 2);
      int p1 = row * LDSW + (g << s) + j;
      int p2 = p1 + quarter, p3 = p1 + 2 * quarter, p4 = p3 + quarter;
      int i1 = j * tstr, i3 = 2 * j * tstr;
      float c1 = twc[i1], s1 = -tws[i1], c3 = twc[i3], s3 = -tws[i3];
      float ar = sRe[p1], ai = sIm[p1], br = sRe[p2], bi = sIm[p2];
      float cr = sRe[p3], ci = sIm[p3], dr = sRe[p4], di = sIm[p4];
      float btr = br * c3 - bi * s3, bti = br * s3 + bi * c3;
      float dtr = dr * c3 - di * s3, dti = dr * s3 + di * c3;
      float Ar = ar + btr, Ai = ai + bti, Br = ar - btr, Bi = ai - bti;
      float Cr = cr + dtr, Ci = ci + dti, Dr = cr - dtr, Di = ci - dti;
      float Ctr = Cr * c1 - Ci * s1, Cti = Cr * s1 + Ci * c1;
      float z0r = Dr * c1 - Di * s1, z0i = Dr * s1 + Di * c1;
      float Dtr = -z0i, Dti = z0r;
      sRe[p1] = Ar + Ctr; sIm[p1] = Ai + Cti;
      sRe[p3] = Ar - Ctr; sIm[p3] = Ai - Cti;
      sRe[p2] = Br + Dtr; sIm[p2] = Bi + Dti;
      sRe[p4] = Br - Dtr; sIm[p4] = Bi - Dti;
    }
  }
  __syncthreads();
  // store real part as bf16
  {
    ushort4* xe = reinterpret_cast<ushort4*>(xenh + (size_t)img * HW);
#pragma unroll
    for (int i = 0; i < 8; ++i) {
      int i4 = t + 512 * i;
      int row = i4 >> 5, colb = (i4 * 4) & 127;
      int p = row * LDSW + colb;
      float4 v; v.x = sRe[p]; v.y = sRe[p + 1]; v.z = sRe[p + 2]; v.w = sRe[p + 3];
      xe[i4] = f4_to_u4(v);
    }
  }
}

// ---------------- output: out = x + sum_m xenh[b,m] * w_out[c,m] (2 px/thread, NT) ----------------
template<bool ISF>
static __device__ __forceinline__ void out_body(const void* x, const float* wl,
                                                const unsigned short* xenh, void* out,
                                                int b, int cs, int pp) {
  float2 e[CMID];
  const unsigned short* xe = xenh + (size_t)(b * CMID) * HW + pp;
#pragma unroll
  for (int m = 0; m < CMID; ++m) {
    unsigned int v = *reinterpret_cast<const unsigned int*>(xe + (size_t)m * HW);
    e[m].x = bf2f((unsigned short)(v & 0xffffu));
    e[m].y = bf2f((unsigned short)(v >> 16));
  }
  const size_t off = (size_t)b * CIN * HW + (size_t)(cs * OCH) * HW + pp;
#pragma unroll 8
  for (int r = 0; r < OCH; ++r) {
    float2 xv = load2g<ISF, true>(x, off + (size_t)r * HW);
#pragma unroll
    for (int m = 0; m < CMID; ++m) {
      float w = wl[r * CMID + m];
      xv.x = fmaf(e[m].x, w, xv.x);
      xv.y = fmaf(e[m].y, w, xv.y);
    }
    if (ISF) {
      union { float2 f; unsigned long long u; } cv; cv.f = xv;
      __builtin_nontemporal_store(cv.u,
          reinterpret_cast<unsigned long long*>((float*)out + off + (size_t)r * HW));
    } else {
      unsigned int o = (unsigned int)f2bf(xv.x) | ((unsigned int)f2bf(xv.y) << 16);
      __builtin_nontemporal_store(o,
          reinterpret_cast<unsigned int*>((unsigned short*)out + off + (size_t)r * HW));
    }
  }
}

__global__ __launch_bounds__(256)
void afe_out_kernel(const void* __restrict__ x, const void* __restrict__ w_out,
                    const unsigned short* __restrict__ xenh, void* __restrict__ out) {
  __shared__ float wl[OCH * CMID];
  int t = threadIdx.x;
  int isf = sniff_isf(x);
  int cs = blockIdx.x & (OSPL - 1);
  int tile = blockIdx.x >> 2;
  int b = tile >> 5;                               // 32 tiles (512 px) per (b,cs)
  int pp = ((tile & 31) << 9) + (t << 1);
  for (int i = t; i < OCH * CMID; i += 256) {
    int r = i >> 4, m = i & 15;
    int src = (cs * OCH + r) * CMID + m;
    wl[i] = isf ? ((const float*)w_out)[src] : bf2f(((const unsigned short*)w_out)[src]);
  }
  __syncthreads();
  if (isf) out_body<true>(x, wl, xenh, out, b, cs, pp);
  else     out_body<false>(x, wl, xenh, out, b, cs, pp);
}

extern "C" void kernel_launch(void* const* d_in, const int* in_sizes, int n_in,
                              void* d_out, int out_size, void* d_ws, size_t ws_size,
                              hipStream_t stream) {
  const void* x      = d_in[0];   // (8,256,128,128)
  const void* w_in   = d_in[1];   // (16,256)
  const void* w_out  = d_in[2];   // (256,16)
  const void* bw     = d_in[3];   // (16,8,9)

  float* G = (float*)d_ws;                                         // 1 MiB fp32
  unsigned short* part = (unsigned short*)(G + CMID * HW);         // 16.8 MiB bf16
  unsigned short* xenh = part + (size_t)CSPL * BB * CMID * HW;     // 4.2 MiB bf16

  hipLaunchKernelGGL(afe_projgain_kernel, dim3(PROJ_BLOCKS + GAIN_BLOCKS), dim3(256), 0, stream,
                     x, w_in, bw, part, G);
  hipLaunchKernelGGL(afe_fft_kernel, dim3(BB * CMID), dim3(512), 0, stream, part, xenh, G);
  hipLaunchKernelGGL(afe_out_kernel, dim3(32 * BB * OSPL), dim3(256), 0, stream, x, w_out, xenh, d_out);
}

// Round 11
// 114.677 us; speedup vs baseline: 1.1286x; 1.0782x over previous
//
#include <hip/hip_runtime.h>
#include <cstdint>
#include <cstddef>

#define BB 8
#define CIN 256
#define CMID 16
#define HH 128
#define WW 128
#define HW 16384
#define NANG 8
#define NRAD 9

#define CSPL 4          // proj channel split
#define CCH  64         // CIN / CSPL
#define OSPL 4          // out channel split
#define OCH  64         // CIN / OSPL

#define PROJ_BLOCKS 1024
#define GAIN_BLOCKS 256

// LDS row stride (floats) for the FFT tile: 129 = 1 mod 32 banks -> with
// row-fastest lane mapping every pass is <=2-way bank aliased (free).
#define LDSW 129

typedef float f32x2 __attribute__((ext_vector_type(2)));

static __device__ __forceinline__ float bf2f(unsigned short u) {
  union { unsigned int i; float f; } c; c.i = ((unsigned int)u) << 16; return c.f;
}
static __device__ __forceinline__ unsigned short f2bf(float f) {
  union { float f; unsigned int i; } c; c.f = f;
  unsigned int r = c.i + 0x7FFFu + ((c.i >> 16) & 1u);
  return (unsigned short)(r >> 16);
}

// 2-element load: ISF=fp32 (8B) else bf16 pair (4B). Plain (temporal) loads:
// x and part are Infinity-Cache-resident between kernels; NT-load hints were
// A/B'd out in R11 (risk: nt bypasses the memory-side cache).
template<bool ISF>
static __device__ __forceinline__ float2 load2g(const void* p, size_t i) {
  float2 r;
  if (ISF) {
    r = *reinterpret_cast<const float2*>((const float*)p + i);
  } else {
    unsigned int v = *reinterpret_cast<const unsigned int*>((const unsigned short*)p + i);
    r.x = bf2f((unsigned short)(v & 0xffffu));
    r.y = bf2f((unsigned short)(v >> 16));
  }
  return r;
}

static __device__ __forceinline__ ushort4 f4_to_u4(float4 v) {
  ushort4 o; o.x = f2bf(v.x); o.y = f2bf(v.y); o.z = f2bf(v.z); o.w = f2bf(v.w);
  return o;
}
static __device__ __forceinline__ float4 u64_to_f4(unsigned long long q) {
  float4 o;
  o.x = bf2f((unsigned short)(q & 0xffffu));
  o.y = bf2f((unsigned short)((q >> 16) & 0xffffu));
  o.z = bf2f((unsigned short)((q >> 32) & 0xffffu));
  o.w = bf2f((unsigned short)(q >> 48));
  return o;
}

// Per-wave dtype sniff (no barrier, no LDS): every wave ballots wild bf16
// exponents over x[0..127]'s low ushorts (fp32 mantissa halves -> ~84% wild;
// bf16 N(0,1) -> ~0%). All waves reach the same verdict -> uniform branch.
static __device__ __forceinline__ int sniff_isf(const void* x) {
  const unsigned short* u16 = (const unsigned short*)x;
  int lane = threadIdx.x & 63;
  unsigned short us = u16[2 * lane];
  int e = (us >> 7) & 0xff;
  unsigned long long m = __ballot(e < 107 || e > 147);
  return (__popcll(m) > 32) ? 1 : 0;
}

// ---------------- gain body (bit-reversed layout, ortho scale folded) ----------------
static __device__ __forceinline__ void gain_body(const void* bw, float* G, int idx, int isf) {
  int m = idx >> 14;
  int p = (idx >> 7) & 127;
  int q = idx & 127;
  int ky = (int)(__brev((unsigned)p) >> 25);
  int kx = (int)(__brev((unsigned)q) >> 25);
  float fy = (float)((ky < 64) ? ky : ky - 128);
  float fx = (float)((kx < 64) ? kx : kx - 128);
  float r = sqrtf(fy * fy + fx * fx);
  int ridx = (int)(r * 0.125f);
  ridx = (ridx > NRAD - 1) ? (NRAD - 1) : ridx;
  const float PI_F = 3.14159265358979323846f;
  float theta = fmodf(atan2f(fy, fx) + PI_F, PI_F);
  const float delta = PI_F / 8.0f;
  const float hwid = 0.75f * delta;
  float wv[NANG]; float s = 0.f;
#pragma unroll
  for (int a = 0; a < NANG; ++a) {
    float center = ((float)a + 0.5f) * delta;
    float dist = fabsf(theta - center);
    float wa = (dist < hwid) ? (1.0f - dist / hwid) : 0.0f;
    wv[a] = wa; s += wa;
  }
  float inv = 1.0f / (s + 1e-8f);
  float g = 0.f;
#pragma unroll
  for (int a = 0; a < NANG; ++a) {
    int o = (m * NANG + a) * NRAD + ridx;
    float bwa = isf ? ((const float*)bw)[o] : bf2f(((const unsigned short*)bw)[o]);
    g += wv[a] * bwa;
  }
  G[idx] = g * inv * (1.0f / 16384.0f);
}

// ---------------- projection (2 px/thread, unroll 8) + gain blocks merged ----------------
// NOTE: no min-waves __launch_bounds__ (R4: VGPR cap 32 -> spills). Keep body
// <=64 VGPR for 8 waves/SIMD (R8: bigger bodies -> 4 waves/SIMD, regression).
// R9: more blocks (NSP=8) neutral-negative; R10: SW pipelining neutral.
template<bool ISF>
static __device__ __forceinline__ void proj_body(const void* x, const float* wl,
                                                 unsigned short* part, int b, int s, int pp) {
  float2 acc[CMID];
#pragma unroll
  for (int m = 0; m < CMID; ++m) { acc[m].x = 0.f; acc[m].y = 0.f; }
  const size_t xbase = (size_t)b * CIN * HW + (size_t)(s * CCH) * HW + pp;
#pragma unroll 8
  for (int cc = 0; cc < CCH; ++cc) {
    float2 xv = load2g<ISF>(x, xbase + (size_t)cc * HW);
#pragma unroll
    for (int m = 0; m < CMID; ++m) {
      float w = wl[m * CCH + cc];
      acc[m].x = fmaf(xv.x, w, acc[m].x);
      acc[m].y = fmaf(xv.y, w, acc[m].y);
    }
  }
  unsigned short* pb = part + ((size_t)(s * BB + b) * CMID) * HW + pp;
#pragma unroll
  for (int m = 0; m < CMID; ++m) {
    unsigned int o = (unsigned int)f2bf(acc[m].x) | ((unsigned int)f2bf(acc[m].y) << 16);
    *reinterpret_cast<unsigned int*>(pb + (size_t)m * HW) = o;
  }
}

__global__ __launch_bounds__(256)
void afe_projgain_kernel(const void* __restrict__ x, const void* __restrict__ w_in,
                         const void* __restrict__ bw,
                         unsigned short* __restrict__ part, float* __restrict__ G) {
  __shared__ float wl[CMID * CCH];
  int t = threadIdx.x;
  int isf = sniff_isf(x);
  if (blockIdx.x >= PROJ_BLOCKS) {
    // gain blocks: 256 blocks x 256 threads x 4 px
    int gb = blockIdx.x - PROJ_BLOCKS;
#pragma unroll
    for (int k = 0; k < 4; ++k) {
      int idx = (gb * 4 + k) * 256 + t;
      gain_body(bw, G, idx, isf);
    }
    return;
  }
  int s = blockIdx.x & (CSPL - 1);
  int tile = blockIdx.x >> 2;
  int b = tile >> 5;                               // 32 tiles (512 px) per (b,s)
  int pp = ((tile & 31) << 9) + (t << 1);
  for (int i = t; i < CMID * CCH; i += 256) {
    int m = i >> 6, cc = i & (CCH - 1);
    int src = m * CIN + s * CCH + cc;
    wl[i] = isf ? ((const float*)w_in)[src] : bf2f(((const unsigned short*)w_in)[src]);
  }
  __syncthreads();
  if (isf) proj_body<true>(x, wl, part, b, s, pp);
  else     proj_body<false>(x, wl, part, b, s, pp);
}

// ---------------- per-image FFT2 -> gain -> IFFT2 ----------------
// Fused two-stage (radix-4-equivalent) passes; pure radix-2 bitrev ordering.
// LDS tile stride = LDSW(129) floats; row passes use row-fastest lane mapping
// so ALL passes are conflict-free (<=2-way aliasing).
__global__ __launch_bounds__(512)
void afe_fft_kernel(const unsigned short* __restrict__ part,
                    unsigned short* __restrict__ xenh,
                    const float* __restrict__ G) {
  __shared__ float sRe[LDSW * HH];
  __shared__ float sIm[LDSW * HH];
  __shared__ float twc[64];
  __shared__ float tws[64];
  int t = threadIdx.x;
  int img = blockIdx.x;                            // b*16 + m
  int m = img & 15;
  const size_t S = (size_t)BB * CMID * HW;
  const unsigned long long* q0 = reinterpret_cast<const unsigned long long*>(part + (size_t)img * HW);
  const unsigned long long* q1 = reinterpret_cast<const unsigned long long*>(part + S + (size_t)img * HW);
  const unsigned long long* q2 = reinterpret_cast<const unsigned long long*>(part + 2 * S + (size_t)img * HW);
  const unsigned long long* q3 = reinterpret_cast<const unsigned long long*>(part + 3 * S + (size_t)img * HW);

#pragma unroll
  for (int i = 0; i < 8; ++i) {
    int i4 = t + 512 * i;                          // float4 index in [0,4096)
    float4 a  = u64_to_f4(q0[i4]);
    float4 b4 = u64_to_f4(q1[i4]);
    float4 c4 = u64_to_f4(q2[i4]);
    float4 d4 = u64_to_f4(q3[i4]);
    int row = i4 >> 5, colb = (i4 * 4) & 127;
    int p = row * LDSW + colb;
    sRe[p]     = a.x + b4.x + c4.x + d4.x;
    sRe[p + 1] = a.y + b4.y + c4.y + d4.y;
    sRe[p + 2] = a.z + b4.z + c4.z + d4.z;
    sRe[p + 3] = a.w + b4.w + c4.w + d4.w;
    sIm[p] = 0.f; sIm[p + 1] = 0.f; sIm[p + 2] = 0.f; sIm[p + 3] = 0.f;
  }
  if (t < 64) {
    const float PI_F = 3.14159265358979323846f;
    float ang = -(2.0f * PI_F / 128.0f) * (float)t;  // W^t = e^{-i 2 pi t/128}
    float sv, cv;
    sincosf(ang, &sv, &cv);
    twc[t] = cv; tws[t] = sv;
  }

  // ---- forward fused passes (stages s, s-1), s = 7,5,3 ----
#pragma unroll
  for (int si = 0; si < 3; ++si) {
    const int s = 7 - 2 * si;
    const int quarter = 1 << (s - 2);
    const int tstr = 1 << (7 - s);
    // rows (row-fastest lanes: conflict-free)
    __syncthreads();
#pragma unroll
    for (int it = 0; it < 8; ++it) {
      int idx = t + 512 * it;                      // 4096 groups
      int row = idx & 127, gg = idx >> 7;
      int j = gg & (quarter - 1), g = gg >> (s - 2);
      int p1 = row * LDSW + (g << s) + j;
      int p2 = p1 + quarter, p3 = p1 + 2 * quarter, p4 = p3 + quarter;
      int i1 = j * tstr, i3 = 2 * j * tstr;
      float c1 = twc[i1], s1 = tws[i1], c3 = twc[i3], s3 = tws[i3];
      float ar = sRe[p1], ai = sIm[p1], br = sRe[p2], bi = sIm[p2];
      float cr = sRe[p3], ci = sIm[p3], dr = sRe[p4], di = sIm[p4];
      float u1r = ar + cr, u1i = ai + ci, t1r = ar - cr, t1i = ai - ci;
      float u2r = br + dr, u2i = bi + di, t2r = br - dr, t2i = bi - di;
      float w1r = t1r * c1 - t1i * s1, w1i = t1r * s1 + t1i * c1;
      float zr = t2r * c1 - t2i * s1, zi = t2r * s1 + t2i * c1;
      float w2r = zi, w2i = -zr;                   // * (-i)
      float e1r = u1r - u2r, e1i = u1i - u2i;
      float e2r = w1r - w2r, e2i = w1i - w2i;
      sRe[p1] = u1r + u2r; sIm[p1] = u1i + u2i;
      sRe[p2] = e1r * c3 - e1i * s3; sIm[p2] = e1r * s3 + e1i * c3;
      sRe[p3] = w1r + w2r; sIm[p3] = w1i + w2i;
      sRe[p4] = e2r * c3 - e2i * s3; sIm[p4] = e2r * s3 + e2i * c3;
    }
    // cols (col-fastest lanes: conflict-free)
    __syncthreads();
#pragma unroll
    for (int it = 0; it < 8; ++it) {
      int idx = t + 512 * it;
      int col = idx & 127, gg = idx >> 7;
      int j = gg & (quarter - 1), g = gg >> (s - 2);
      int p1 = ((g << s) + j) * LDSW + col;
      int p2 = p1 + quarter * LDSW, p3 = p1 + 2 * quarter * LDSW, p4 = p1 + 3 * quarter * LDSW;
      int i1 = j * tstr, i3 = 2 * j * tstr;
      float c1 = twc[i1], s1 = tws[i1], c3 = twc[i3], s3 = tws[i3];
      float ar = sRe[p1], ai = sIm[p1], br = sRe[p2], bi = sIm[p2];
      float cr = sRe[p3], ci = sIm[p3], dr = sRe[p4], di = sIm[p4];
      float u1r = ar + cr, u1i = ai + ci, t1r = ar - cr, t1i = ai - ci;
      float u2r = br + dr, u2i = bi + di, t2r = br - dr, t2i = bi - di;
      float w1r = t1r * c1 - t1i * s1, w1i = t1r * s1 + t1i * c1;
      float zr = t2r * c1 - t2i * s1, zi = t2r * s1 + t2i * c1;
      float w2r = zi, w2i = -zr;
      float e1r = u1r - u2r, e1i = u1i - u2i;
      float e2r = w1r - w2r, e2i = w1i - w2i;
      sRe[p1] = u1r + u2r; sIm[p1] = u1i + u2i;
      sRe[p2] = e1r * c3 - e1i * s3; sIm[p2] = e1r * s3 + e1i * c3;
      sRe[p3] = w1r + w2r; sIm[p3] = w1i + w2i;
      sRe[p4] = e2r * c3 - e2i * s3; sIm[p4] = e2r * s3 + e2i * c3;
    }
  }
  // ---- forward stage 1 (no twiddle), rows then cols, then gain ----
  __syncthreads();
#pragma unroll
  for (int it = 0; it < 16; ++it) {
    int idx = t + 512 * it;                        // 8192 pairs
    int row = idx & 127, k = idx >> 7;             // k in [0,64)
    int p1 = row * LDSW + (k << 1), p2 = p1 + 1;
    float ur = sRe[p1], ui = sIm[p1], vr = sRe[p2], vi = sIm[p2];
    sRe[p1] = ur + vr; sIm[p1] = ui + vi;
    sRe[p2] = ur - vr; sIm[p2] = ui - vi;
  }
  __syncthreads();
#pragma unroll
  for (int it = 0; it < 16; ++it) {
    int idx = t + 512 * it;
    int col = idx & 127, k = idx >> 7;             // k in [0,64)
    int p1 = (k << 1) * LDSW + col, p2 = p1 + LDSW;
    float ur = sRe[p1], ui = sIm[p1], vr = sRe[p2], vi = sIm[p2];
    sRe[p1] = ur + vr; sIm[p1] = ui + vi;
    sRe[p2] = ur - vr; sIm[p2] = ui - vi;
  }
  __syncthreads();
  {
    const float4* Gm = reinterpret_cast<const float4*>(G + m * HW);
#pragma unroll
    for (int it = 0; it < 8; ++it) {
      int i4 = t + 512 * it;
      float4 g = Gm[i4];
      int row = i4 >> 5, colb = (i4 * 4) & 127;
      int p = row * LDSW + colb;
      sRe[p] *= g.x; sIm[p] *= g.x;
      sRe[p + 1] *= g.y; sIm[p + 1] *= g.y;
      sRe[p + 2] *= g.z; sIm[p + 2] *= g.z;
      sRe[p + 3] *= g.w; sIm[p + 3] *= g.w;
    }
  }
  // ---- inverse stage 1 cols ----
  __syncthreads();
#pragma unroll
  for (int it = 0; it < 16; ++it) {
    int idx = t + 512 * it;
    int col = idx & 127, k = idx >> 7;
    int p1 = (k << 1) * LDSW + col, p2 = p1 + LDSW;
    float ur = sRe[p1], ui = sIm[p1], vr = sRe[p2], vi = sIm[p2];
    sRe[p1] = ur + vr; sIm[p1] = ui + vi;
    sRe[p2] = ur - vr; sIm[p2] = ui - vi;
  }
  // inverse fused passes (stages s-1 then s), s = 3,5,7 — cols
#pragma unroll
  for (int si = 0; si < 3; ++si) {
    const int s = 3 + 2 * si;
    const int quarter = 1 << (s - 2);
    const int tstr = 1 << (7 - s);
    __syncthreads();
#pragma unroll
    for (int it = 0; it < 8; ++it) {
      int idx = t + 512 * it;
      int col = idx & 127, gg = idx >> 7;
      int j = gg & (quarter - 1), g = gg >> (s - 2);
      int p1 = ((g << s) + j) * LDSW + col;
      int p2 = p1 + quarter * LDSW, p3 = p1 + 2 * quarter * LDSW, p4 = p1 + 3 * quarter * LDSW;
      int i1 = j * tstr, i3 = 2 * j * tstr;
      float c1 = twc[i1], s1 = -tws[i1], c3 = twc[i3], s3 = -tws[i3];  // conj
      float ar = sRe[p1], ai = sIm[p1], br = sRe[p2], bi = sIm[p2];
      float cr = sRe[p3], ci = sIm[p3], dr = sRe[p4], di = sIm[p4];
      float btr = br * c3 - bi * s3, bti = br * s3 + bi * c3;
      float dtr = dr * c3 - di * s3, dti = dr * s3 + di * c3;
      float Ar = ar + btr, Ai = ai + bti, Br = ar - btr, Bi = ai - bti;
      float Cr = cr + dtr, Ci = ci + dti, Dr = cr - dtr, Di = ci - dti;
      float Ctr = Cr * c1 - Ci * s1, Cti = Cr * s1 + Ci * c1;
      float z0r = Dr * c1 - Di * s1, z0i = Dr * s1 + Di * c1;
      float Dtr = -z0i, Dti = z0r;                 // * (+i)
      sRe[p1] = Ar + Ctr; sIm[p1] = Ai + Cti;
      sRe[p3] = Ar - Ctr; sIm[p3] = Ai - Cti;
      sRe[p2] = Br + Dtr; sIm[p2] = Bi + Dti;
      sRe[p4] = Br - Dtr; sIm[p4] = Bi - Dti;
    }
  }
  // inverse stage 1 rows
  __syncthreads();
#pragma unroll
  for (int it = 0; it < 16; ++it) {
    int idx = t + 512 * it;
    int row = idx & 127, k = idx >> 7;
    int p1 = row * LDSW + (k << 1), p2 = p1 + 1;
    float ur = sRe[p1], ui = sIm[p1], vr = sRe[p2], vi = sIm[p2];
    sRe[p1] = ur + vr; sIm[p1] = ui + vi;
    sRe[p2] = ur - vr; sIm[p2] = ui - vi;
  }
  // inverse fused passes — rows
#pragma unroll
  for (int si = 0; si < 3; ++si) {
    const int s = 3 + 2 * si;
    const int quarter = 1 << (s - 2);
    const int tstr = 1 << (7 - s);
    __syncthreads();
#pragma unroll
    for (int it = 0; it < 8; ++it) {
      int idx = t + 512 * it;
      int row = idx & 127, gg = idx >> 7;
      int j = gg & (quarter - 1), g = gg >> (s - 2);
      int p1 = row * LDSW + (g << s) + j;
      int p2 = p1 + quarter, p3 = p1 + 2 * quarter, p4 = p3 + quarter;
      int i1 = j * tstr, i3 = 2 * j * tstr;
      float c1 = twc[i1], s1 = -tws[i1], c3 = twc[i3], s3 = -tws[i3];
      float ar = sRe[p1], ai = sIm[p1], br = sRe[p2], bi = sIm[p2];
      float cr = sRe[p3], ci = sIm[p3], dr = sRe[p4], di = sIm[p4];
      float btr = br * c3 - bi * s3, bti = br * s3 + bi * c3;
      float dtr = dr * c3 - di * s3, dti = dr * s3 + di * c3;
      float Ar = ar + btr, Ai = ai + bti, Br = ar - btr, Bi = ai - bti;
      float Cr = cr + dtr, Ci = ci + dti, Dr = cr - dtr, Di = ci - dti;
      float Ctr = Cr * c1 - Ci * s1, Cti = Cr * s1 + Ci * c1;
      float z0r = Dr * c1 - Di * s1, z0i = Dr * s1 + Di * c1;
      float Dtr = -z0i, Dti = z0r;
      sRe[p1] = Ar + Ctr; sIm[p1] = Ai + Cti;
      sRe[p3] = Ar - Ctr; sIm[p3] = Ai - Cti;
      sRe[p2] = Br + Dtr; sIm[p2] = Bi + Dti;
      sRe[p4] = Br - Dtr; sIm[p4] = Bi - Dti;
    }
  }
  __syncthreads();
  // store real part as bf16
  {
    ushort4* xe = reinterpret_cast<ushort4*>(xenh + (size_t)img * HW);
#pragma unroll
    for (int i = 0; i < 8; ++i) {
      int i4 = t + 512 * i;
      int row = i4 >> 5, colb = (i4 * 4) & 127;
      int p = row * LDSW + colb;
      float4 v; v.x = sRe[p]; v.y = sRe[p + 1]; v.z = sRe[p + 2]; v.w = sRe[p + 3];
      xe[i4] = f4_to_u4(v);
    }
  }
}

// ---------------- output: out = x + sum_m xenh[b,m] * w_out[c,m] (2 px/thread) ----------------
// x loads: normal/temporal (x is L3-resident after proj). Stores: NT (write-once).
template<bool ISF>
static __device__ __forceinline__ void out_body(const void* x, const float* wl,
                                                const unsigned short* xenh, void* out,
                                                int b, int cs, int pp) {
  float2 e[CMID];
  const unsigned short* xe = xenh + (size_t)(b * CMID) * HW + pp;
#pragma unroll
  for (int m = 0; m < CMID; ++m) {
    unsigned int v = *reinterpret_cast<const unsigned int*>(xe + (size_t)m * HW);
    e[m].x = bf2f((unsigned short)(v & 0xffffu));
    e[m].y = bf2f((unsigned short)(v >> 16));
  }
  const size_t off = (size_t)b * CIN * HW + (size_t)(cs * OCH) * HW + pp;
#pragma unroll 8
  for (int r = 0; r < OCH; ++r) {
    float2 xv = load2g<ISF>(x, off + (size_t)r * HW);
#pragma unroll
    for (int m = 0; m < CMID; ++m) {
      float w = wl[r * CMID + m];
      xv.x = fmaf(e[m].x, w, xv.x);
      xv.y = fmaf(e[m].y, w, xv.y);
    }
    if (ISF) {
      union { float2 f; unsigned long long u; } cv; cv.f = xv;
      __builtin_nontemporal_store(cv.u,
          reinterpret_cast<unsigned long long*>((float*)out + off + (size_t)r * HW));
    } else {
      unsigned int o = (unsigned int)f2bf(xv.x) | ((unsigned int)f2bf(xv.y) << 16);
      __builtin_nontemporal_store(o,
          reinterpret_cast<unsigned int*>((unsigned short*)out + off + (size_t)r * HW));
    }
  }
}

__global__ __launch_bounds__(256)
void afe_out_kernel(const void* __restrict__ x, const void* __restrict__ w_out,
                    const unsigned short* __restrict__ xenh, void* __restrict__ out) {
  __shared__ float wl[OCH * CMID];
  int t = threadIdx.x;
  int isf = sniff_isf(x);
  int cs = blockIdx.x & (OSPL - 1);
  int tile = blockIdx.x >> 2;
  int b = tile >> 5;                               // 32 tiles (512 px) per (b,cs)
  int pp = ((tile & 31) << 9) + (t << 1);
  for (int i = t; i < OCH * CMID; i += 256) {
    int r = i >> 4, m = i & 15;
    int src = (cs * OCH + r) * CMID + m;
    wl[i] = isf ? ((const float*)w_out)[src] : bf2f(((const unsigned short*)w_out)[src]);
  }
  __syncthreads();
  if (isf) out_body<true>(x, wl, xenh, out, b, cs, pp);
  else     out_body<false>(x, wl, xenh, out, b, cs, pp);
}

extern "C" void kernel_launch(void* const* d_in, const int* in_sizes, int n_in,
                              void* d_out, int out_size, void* d_ws, size_t ws_size,
                              hipStream_t stream) {
  const void* x      = d_in[0];   // (8,256,128,128)
  const void* w_in   = d_in[1];   // (16,256)
  const void* w_out  = d_in[2];   // (256,16)
  const void* bw     = d_in[3];   // (16,8,9)

  float* G = (float*)d_ws;                                         // 1 MiB fp32
  unsigned short* part = (unsigned short*)(G + CMID * HW);         // 16.8 MiB bf16
  unsigned short* xenh = part + (size_t)CSPL * BB * CMID * HW;     // 4.2 MiB bf16

  hipLaunchKernelGGL(afe_projgain_kernel, dim3(PROJ_BLOCKS + GAIN_BLOCKS), dim3(256), 0, stream,
                     x, w_in, bw, part, G);
  hipLaunchKernelGGL(afe_fft_kernel, dim3(BB * CMID), dim3(512), 0, stream, part, xenh, G);
  hipLaunchKernelGGL(afe_out_kernel, dim3(32 * BB * OSPL), dim3(256), 0, stream, x, w_out, xenh, d_out);
}